// Round 1
// baseline (253.095 us; speedup 1.0000x reference)
//
#include <hip/hip_runtime.h>
#include <math.h>

#define NN 257
#define NN2 66049  // 257*257

__device__ __forceinline__ double lam_of(int c) {
    return c == 0 ? 610e-9 : (c == 1 ? 530e-9 : 470e-9);
}

static const double D_PI = 3.14159265358979323846;

// ---------------- kernel 1: z1 = mean(depth); zero psums ----------------
__global__ __launch_bounds__(256) void k_reduce_depth(const float* __restrict__ depth, double* zs) {
    __shared__ double s[256];
    double acc = 0.0;
    for (int i = threadIdx.x; i < 16384; i += 256) acc += (double)depth[i];
    s[threadIdx.x] = acc;
    __syncthreads();
    for (int o = 128; o > 0; o >>= 1) {
        if (threadIdx.x < o) s[threadIdx.x] += s[threadIdx.x + o];
        __syncthreads();
    }
    if (threadIdx.x == 0) {
        zs[0] = s[0] / 16384.0;
        zs[1] = 0.0; zs[2] = 0.0; zs[3] = 0.0;  // psf sums per channel
    }
}

// ---------------- kernel 2: build w = fftshift(u) ----------------
// w[c][j][i] = u[(j+129)%257][(i+129)%257], u = exp(i k sqrt(R2+z1^2)) * A
__global__ __launch_bounds__(256) void k_build_w(const double* __restrict__ zs, float2* __restrict__ w) {
    int idx = blockIdx.x * 256 + threadIdx.x;
    if (idx >= 3 * NN2) return;
    int c = idx / NN2;
    int r = idx - c * NN2;
    int j = r / NN, i = r - j * NN;
    int js = j + 129; if (js >= NN) js -= NN;
    int is = i + 129; if (is >= NN) is -= NN;
    const double step = 0.01 / 256.0;           // linspace step, 257 pts over [-L/2, L/2]
    double x = -0.005 + is * step;
    double y = -0.005 + js * step;
    double r2 = x * x + y * y;
    const double ap = 0.5 * (0.01 / 257.0) * 128.0 + 1e-7;  // ap_radius + eps
    float2 o = make_float2(0.f, 0.f);
    if (sqrt(r2) <= ap) {
        double z1 = zs[0];
        double lam = lam_of(c);
        double k = 2.0 * D_PI / lam;
        double th = fmod(k * sqrt(r2 + z1 * z1), 2.0 * D_PI);
        double sv, cv;
        sincos(th, &sv, &cv);
        o = make_float2((float)cv, (float)sv);
    }
    w[idx] = o;
}

// ---------------- kernel 3: O-pass (column DFT + transpose) ----------------
// out[c][b][a] = sum_t in[c][t][b] * exp(SIGN * 2*pi*i * a*t / 257)
template <int SIGN>
__global__ __launch_bounds__(256) void k_dft(const float2* __restrict__ in, float2* __restrict__ out) {
    __shared__ float2 col[NN];
    __shared__ float2 tw[NN];
    int cb = blockIdx.x;
    int c = cb / NN, b = cb - c * NN;
    const float2* inp = in + c * NN2;
    for (int t = threadIdx.x; t < NN; t += 256) {
        col[t] = inp[t * NN + b];
        double ang = (double)SIGN * (2.0 * D_PI / 257.0) * (double)t;
        double sv, cv;
        sincos(ang, &sv, &cv);
        tw[t] = make_float2((float)cv, (float)sv);
    }
    __syncthreads();
    for (int a = threadIdx.x; a < NN; a += 256) {
        float accx = 0.f, accy = 0.f;
        int m = 0;
        for (int t = 0; t < NN; ++t) {
            float2 cv = col[t];
            float2 tv = tw[m];
            accx = fmaf(cv.x, tv.x, accx);
            accx = fmaf(-cv.y, tv.y, accx);
            accy = fmaf(cv.x, tv.y, accy);
            accy = fmaf(cv.y, tv.x, accy);
            m += a; if (m >= NN) m -= NN;
        }
        out[(c * NN + b) * NN + a] = make_float2(accx, accy);
    }
}

// ---------------- kernel 4: U *= fftshift(H) ----------------
__global__ __launch_bounds__(256) void k_hmul(float2* __restrict__ U) {
    int idx = blockIdx.x * 256 + threadIdx.x;
    if (idx >= 3 * NN2) return;
    int c = idx / NN2;
    int r = idx - c * NN2;
    int p = r / NN, q = r - p * NN;
    int ps = p + 129; if (ps >= NN) ps -= NN;
    int qs = q + 129; if (qs >= NN) qs -= NN;
    const double fstep = 25700.0 / 256.0;  // linspace(-12850, 12850, 257)
    double fy = -12850.0 + ps * fstep;
    double fx = -12850.0 + qs * fstep;
    double lam = lam_of(c);
    double lfx = lam * fx, lfy = lam * fy;
    double a2 = 1.0 - lfx * lfx - lfy * lfy;
    float2 h = make_float2(0.f, 0.f);
    if (fx * fx + fy * fy < 1.0 / (lam * lam)) {
        double kz = 2.0 * D_PI / lam * 0.05;
        double ph = fmod(kz * sqrt(a2 > 0.0 ? a2 : 0.0), 2.0 * D_PI);
        double sv, cv;
        sincos(ph, &sv, &cv);
        h = make_float2((float)cv, (float)sv);
    }
    float2 u = U[idx];
    U[idx] = make_float2(u.x * h.x - u.y * h.y, u.x * h.y + u.y * h.x);
}

// ---------------- kernel 5: psf_raw = |ifftshift(u2)|^2 / N^4; accumulate sums ----------------
__global__ __launch_bounds__(256) void k_psf_raw(const float2* __restrict__ u2, float* __restrict__ raw,
                                                 double* __restrict__ zs) {
    int c = blockIdx.y;
    int idx = blockIdx.x * 256 + threadIdx.x;
    double val = 0.0;
    if (idx < NN2) {
        int j = idx / NN, i = idx - j * NN;
        int js = j + 128; if (js >= NN) js -= NN;
        int is = i + 128; if (is >= NN) is -= NN;
        float2 v = u2[c * NN2 + js * NN + is];
        const double invn4 = 1.0 / ((double)NN2 * (double)NN2);
        double m = ((double)v.x * v.x + (double)v.y * v.y) * invn4;
        raw[c * NN2 + idx] = (float)m;
        val = m;
    }
    __shared__ double s[256];
    s[threadIdx.x] = val;
    __syncthreads();
    for (int o = 128; o > 0; o >>= 1) {
        if (threadIdx.x < o) s[threadIdx.x] += s[threadIdx.x + o];
        __syncthreads();
    }
    if (threadIdx.x == 0) atomicAdd(&zs[1 + c], s[0]);
}

// ---------------- kernel 6: normalize; write psf output (channel-last) + planar copy ----------------
__global__ __launch_bounds__(256) void k_psf_norm(const float* __restrict__ raw, const double* __restrict__ zs,
                                                  float* __restrict__ psf_planar, float* __restrict__ out_psf) {
    int c = blockIdx.y;
    int idx = blockIdx.x * 256 + threadIdx.x;
    if (idx >= NN2) return;
    float inv = (float)(1.0 / (zs[1 + c] + 1e-7));
    float v = raw[c * NN2 + idx] * inv;
    psf_planar[c * NN2 + idx] = v;
    out_psf[idx * 3 + c] = v;
}

// ---------------- kernel 7: direct SAME cross-correlation (partial over u-chunk) ----------------
// out[y][x][c] = sum_{u,v} img[u][v][c] * psf[c][(u-y)+128][(v-x)+128]
__global__ __launch_bounds__(128) void k_conv(const float* __restrict__ img, const float* __restrict__ psf,
                                              float* __restrict__ part) {
    __shared__ float imgrow[128];
    __shared__ float prow[NN];
    int y = blockIdx.x, c = blockIdx.y, us = blockIdx.z;
    int x = threadIdx.x;
    float acc = 0.f;
    for (int u = us * 32; u < us * 32 + 32; ++u) {
        imgrow[x] = img[(u * 128 + x) * 3 + c];
        int ky = u - y + 128;  // always in [1,255]
        const float* pr = psf + c * NN2 + ky * NN;
        prow[x] = pr[x];
        prow[x + 128] = pr[x + 128];
        if (x == 0) prow[256] = pr[256];
        __syncthreads();
        #pragma unroll 8
        for (int v = 0; v < 128; ++v) acc = fmaf(imgrow[v], prow[v - x + 128], acc);
        __syncthreads();
    }
    part[((us * 3 + c) * 128 + y) * 128 + x] = acc;
}

// ---------------- kernel 8: combine conv partials -> out image ----------------
__global__ __launch_bounds__(256) void k_combine(const float* __restrict__ part, float* __restrict__ out) {
    int o = blockIdx.x * 256 + threadIdx.x;
    if (o >= 49152) return;
    int c = o % 3;
    int r = o / 3;
    int y = r / 128, x = r - y * 128;
    float s = 0.f;
    for (int us = 0; us < 4; ++us) s += part[((us * 3 + c) * 128 + y) * 128 + x];
    out[o] = s;
}

extern "C" void kernel_launch(void* const* d_in, const int* in_sizes, int n_in,
                              void* d_out, int out_size, void* d_ws, size_t ws_size,
                              hipStream_t stream) {
    const float* img = (const float*)d_in[0];    // (128,128,3) f32
    const float* depth = (const float*)d_in[1];  // (128,128) f32
    float* out = (float*)d_out;                  // 49152 (image) + 198147 (psf)

    char* ws = (char*)d_ws;
    double* zs = (double*)ws;                              // [0]=z1, [1..3]=psf sums
    float2* bufA = (float2*)(ws + 64);                     // 3*66049 complex
    float2* bufB = bufA + 3 * NN2;                         // 3*66049 complex
    float* raw = (float*)(bufB + 3 * NN2);                 // 3*66049 f32
    float* psfp = raw + 3 * NN2;                           // 3*66049 f32 (planar normalized)
    float* part = psfp + 3 * NN2;                          // 4*3*128*128 f32

    k_reduce_depth<<<1, 256, 0, stream>>>(depth, zs);
    k_build_w<<<(3 * NN2 + 255) / 256, 256, 0, stream>>>(zs, bufA);
    k_dft<-1><<<3 * NN, 256, 0, stream>>>(bufA, bufB);
    k_dft<-1><<<3 * NN, 256, 0, stream>>>(bufB, bufA);
    k_hmul<<<(3 * NN2 + 255) / 256, 256, 0, stream>>>(bufA);
    k_dft<1><<<3 * NN, 256, 0, stream>>>(bufA, bufB);
    k_dft<1><<<3 * NN, 256, 0, stream>>>(bufB, bufA);
    k_psf_raw<<<dim3(259, 3), 256, 0, stream>>>(bufA, raw, zs);
    k_psf_norm<<<dim3(259, 3), 256, 0, stream>>>(raw, zs, psfp, out + 49152);
    k_conv<<<dim3(128, 3, 4), 128, 0, stream>>>(img, psfp, part);
    k_combine<<<(49152 + 255) / 256, 256, 0, stream>>>(part, out);
}

// Round 2
// 185.310 us; speedup vs baseline: 1.3658x; 1.3658x over previous
//
#include <hip/hip_runtime.h>
#include <math.h>

#define NN 257
#define NN2 66049        // 257*257
#define PROW 260         // padded psf row stride (floats), 16B-aligned rows
#define PCH (PROW * NN)  // floats per psf channel

static const double D_PI = 3.14159265358979323846;

__device__ __forceinline__ double lam_of(int c) {
    return c == 0 ? 610e-9 : (c == 1 ? 530e-9 : 470e-9);
}

// ---------------- kernel 1: z1 = mean(depth); zero psf sums ----------------
__global__ __launch_bounds__(256) void k_reduce_depth(const float* __restrict__ depth, double* zs) {
    __shared__ double s[256];
    double acc = 0.0;
    for (int i = threadIdx.x; i < 16384; i += 256) acc += (double)depth[i];
    s[threadIdx.x] = acc;
    __syncthreads();
    for (int o = 128; o > 0; o >>= 1) {
        if (threadIdx.x < o) s[threadIdx.x] += s[threadIdx.x + o];
        __syncthreads();
    }
    if (threadIdx.x == 0) {
        zs[0] = s[0] / 16384.0;
        zs[1] = 0.0; zs[2] = 0.0; zs[3] = 0.0;
    }
}

// ---------------- fused DFT pass ----------------
// out[c][b][a] = sum_t colval(t) * exp(SIGN*2*pi*i*a*t/257)
// MODE 0: colval generated analytically (fftshift'd aperture field), no input read
// MODE 1: colval = in[c][t][b]
// MODE 2: colval = in[c][t][b] * fftshift(H)(t,b)
// MODE 3: like 1, but epilogue writes |.|^2/N^4 ifftshift'd to raw + channel sums
template <int SIGN, int MODE>
__global__ __launch_bounds__(256) void k_dft(const float2* __restrict__ in, float2* __restrict__ out,
                                             const double* __restrict__ zs, float* __restrict__ raw,
                                             double* __restrict__ sums) {
    __shared__ float2 col[NN];
    __shared__ float2 red[4];
    __shared__ double redd[4];
    const int c = blockIdx.y;
    const int b = blockIdx.x;
    const int tid = threadIdx.x;

    // ---- stage column (with fused generation / H-multiply) ----
    for (int t = tid; t < NN; t += 256) {
        float2 v;
        if (MODE == 0) {
            int js = t + 129; if (js >= NN) js -= NN;
            int is = b + 129; if (is >= NN) is -= NN;
            const double step = 0.01 / 256.0;
            double x = -0.005 + is * step;
            double y = -0.005 + js * step;
            double r2 = x * x + y * y;
            const double ap = 0.5 * (0.01 / 257.0) * 128.0 + 1e-7;
            v = make_float2(0.f, 0.f);
            if (sqrt(r2) <= ap) {
                double z1 = zs[0];
                double lam = lam_of(c);
                double th = fmod(2.0 * D_PI / lam * sqrt(r2 + z1 * z1), 2.0 * D_PI);
                double sv, cv; sincos(th, &sv, &cv);
                v = make_float2((float)cv, (float)sv);
            }
        } else {
            v = in[(c * NN + t) * NN + b];
            if (MODE == 2) {
                int ps = t + 129; if (ps >= NN) ps -= NN;
                int qs = b + 129; if (qs >= NN) qs -= NN;
                const double fstep = 25700.0 / 256.0;
                double fy = -12850.0 + ps * fstep;
                double fx = -12850.0 + qs * fstep;
                double lam = lam_of(c);
                double lfx = lam * fx, lfy = lam * fy;
                double a2 = 1.0 - lfx * lfx - lfy * lfy;
                float2 h = make_float2(0.f, 0.f);
                if (fx * fx + fy * fy < 1.0 / (lam * lam)) {
                    double ph = fmod(2.0 * D_PI / lam * 0.05 * sqrt(a2 > 0.0 ? a2 : 0.0), 2.0 * D_PI);
                    double sv, cv; sincos(ph, &sv, &cv);
                    h = make_float2((float)cv, (float)sv);
                }
                v = make_float2(v.x * h.x - v.y * h.y, v.x * h.y + v.y * h.x);
            }
        }
        col[t] = v;
    }
    __syncthreads();

    const float invn4 = (float)(1.0 / ((double)NN2 * (double)NN2));
    const int a = tid;  // output index 0..255 (256 handled by reduction below)

    // two independent twiddle chains (even/odd t) for ILP
    double base = (double)SIGN * (2.0 * D_PI / 257.0) * (double)a;
    double sv0, cv0; sincos(base, &sv0, &cv0);
    double sv2, cv2; sincos(2.0 * base, &sv2, &cv2);
    const float w2x = (float)cv2, w2y = (float)sv2;
    float c0x = 1.f, c0y = 0.f;                       // omega^{a*0}
    float c1x = (float)cv0, c1y = (float)sv0;         // omega^{a*1}
    float aAx = 0.f, aAy = 0.f, aBx = 0.f, aBy = 0.f;

    for (int t = 0; t < 256; t += 2) {
        if ((t & 31) == 0 && t) {  // periodic refresh against f32 drift
            int m0 = (a * t) % NN;
            int m1 = (a * (t + 1)) % NN;
            float g0 = (float)((double)SIGN * (2.0 * D_PI / 257.0) * m0);
            float g1 = (float)((double)SIGN * (2.0 * D_PI / 257.0) * m1);
            sincosf(g0, &c0y, &c0x);
            sincosf(g1, &c1y, &c1x);
        }
        float2 v0 = col[t];
        float2 v1 = col[t + 1];
        aAx = fmaf(v0.x, c0x, aAx); aAx = fmaf(-v0.y, c0y, aAx);
        aAy = fmaf(v0.x, c0y, aAy); aAy = fmaf(v0.y, c0x, aAy);
        aBx = fmaf(v1.x, c1x, aBx); aBx = fmaf(-v1.y, c1y, aBx);
        aBy = fmaf(v1.x, c1y, aBy); aBy = fmaf(v1.y, c1x, aBy);
        float n0x = c0x * w2x - c0y * w2y;
        float n0y = c0x * w2y + c0y * w2x;
        float n1x = c1x * w2x - c1y * w2y;
        float n1y = c1x * w2y + c1y * w2x;
        c0x = n0x; c0y = n0y; c1x = n1x; c1y = n1y;
    }
    // leftover t=256 (c0 chain now holds omega^{a*256})
    {
        float2 v = col[256];
        aAx = fmaf(v.x, c0x, aAx); aAx = fmaf(-v.y, c0y, aAx);
        aAy = fmaf(v.x, c0y, aAy); aAy = fmaf(v.y, c0x, aAy);
    }
    float ax = aAx + aBx, ay = aAy + aBy;

    double sum_local = 0.0;
    if (MODE < 3) {
        out[(c * NN + b) * NN + a] = make_float2(ax, ay);
    } else {
        int jj = b + 129; if (jj >= NN) jj -= NN;
        int ii = a + 129; if (ii >= NN) ii -= NN;
        float m = fmaf(ax, ax, ay * ay) * invn4;
        raw[c * PCH + jj * PROW + ii] = m;
        sum_local = (double)m;
    }

    // ---- a = 256 output: omega^{256 t} = omega^{-t}; parallel reduce ----
    float tx_, ty_;
    {
        int t = tid;
        float ang = (float)(-(double)SIGN * (2.0 * D_PI / 257.0) * (double)t);
        float s_, c_; sincosf(ang, &s_, &c_);
        float2 cv = col[t];
        tx_ = cv.x * c_ - cv.y * s_;
        ty_ = cv.x * s_ + cv.y * c_;
        if (tid == 0) {
            float ang2 = (float)(-(double)SIGN * (2.0 * D_PI / 257.0) * 256.0);
            sincosf(ang2, &s_, &c_);
            cv = col[256];
            tx_ += cv.x * c_ - cv.y * s_;
            ty_ += cv.x * s_ + cv.y * c_;
        }
    }
    for (int o = 32; o > 0; o >>= 1) {
        tx_ += __shfl_down(tx_, o);
        ty_ += __shfl_down(ty_, o);
    }
    int wid = tid >> 6;
    if ((tid & 63) == 0) red[wid] = make_float2(tx_, ty_);
    __syncthreads();
    if (tid == 0) {
        float Xx = red[0].x + red[1].x + red[2].x + red[3].x;
        float Xy = red[0].y + red[1].y + red[2].y + red[3].y;
        if (MODE < 3) {
            out[(c * NN + b) * NN + 256] = make_float2(Xx, Xy);
        } else {
            int jj = b + 129; if (jj >= NN) jj -= NN;
            float m = fmaf(Xx, Xx, Xy * Xy) * invn4;
            raw[c * PCH + jj * PROW + 128] = m;  // (256+129)%257 == 128
            sum_local += (double)m;
        }
    }

    if (MODE == 3) {
        double s = sum_local;
        for (int o = 32; o > 0; o >>= 1) s += __shfl_down(s, o);
        if ((tid & 63) == 0) redd[wid] = s;
        __syncthreads();
        if (tid == 0) atomicAdd(&sums[c], redd[0] + redd[1] + redd[2] + redd[3]);
    }
}

// ---------------- normalize psf in place (padded planar) + write interleaved output ----------------
__global__ __launch_bounds__(256) void k_psf_norm(float* __restrict__ raw, const double* __restrict__ zs,
                                                  float* __restrict__ out_psf) {
    int c = blockIdx.y;
    int idx = blockIdx.x * 256 + threadIdx.x;
    if (idx >= NN2) return;
    int j = idx / NN, i = idx - j * NN;
    float inv = (float)(1.0 / (zs[1 + c] + 1e-7));
    float v = raw[c * PCH + j * PROW + i] * inv;
    raw[c * PCH + j * PROW + i] = v;
    out_psf[idx * 3 + c] = v;
}

// ---------------- register-tiled direct SAME cross-correlation ----------------
// out[y][x][c] = sum_{u,v} img[u][v][c] * psf[c][u-y+128][v-x+128]
// thread owns 4 consecutive x outputs; psf via aligned float4 sliding window (global, L2-hot)
__global__ __launch_bounds__(64) void k_conv(const float* __restrict__ img, const float* __restrict__ psf,
                                             float* __restrict__ part) {
    __shared__ float imgrow[8][128];
    const int by = blockIdx.x;   // 0..63 (y-pairs)
    const int c = blockIdx.y;
    const int uz = blockIdx.z;   // 0..15 (u chunks of 8)
    const int tid = threadIdx.x;
    const int ty = tid >> 5, tx = tid & 31;
    const int y = 2 * by + ty;
    const int u0 = uz * 8;

    for (int k = tid; k < 1024; k += 64) {
        int uu = k >> 7, v = k & 127;
        imgrow[uu][v] = img[((u0 + uu) * 128 + v) * 3 + c];
    }
    __syncthreads();

    const int x4 = 4 * tx;
    const int j0 = 128 - x4;
    float a0 = 0.f, a1 = 0.f, a2 = 0.f, a3 = 0.f;

    for (int u = 0; u < 8; ++u) {
        int ky = (u0 + u) - y + 128;  // in [1,255]
        const float* pb = psf + c * PCH + ky * PROW;
        float4 A = *(const float4*)(pb + j0 - 4);
        #pragma unroll 8
        for (int m2 = 0; m2 < 32; ++m2) {
            float4 B = *(const float4*)(pb + j0 + 4 * m2);
            float4 iv = *(const float4*)(&imgrow[u][4 * m2]);
            a0 = fmaf(iv.x, B.x, a0); a1 = fmaf(iv.x, A.w, a1); a2 = fmaf(iv.x, A.z, a2); a3 = fmaf(iv.x, A.y, a3);
            a0 = fmaf(iv.y, B.y, a0); a1 = fmaf(iv.y, B.x, a1); a2 = fmaf(iv.y, A.w, a2); a3 = fmaf(iv.y, A.z, a3);
            a0 = fmaf(iv.z, B.z, a0); a1 = fmaf(iv.z, B.y, a1); a2 = fmaf(iv.z, B.x, a2); a3 = fmaf(iv.z, A.w, a3);
            a0 = fmaf(iv.w, B.w, a0); a1 = fmaf(iv.w, B.z, a1); a2 = fmaf(iv.w, B.y, a2); a3 = fmaf(iv.w, B.x, a3);
            A = B;
        }
    }
    *(float4*)(part + ((uz * 3 + c) * 128 + y) * 128 + x4) = make_float4(a0, a1, a2, a3);
}

// ---------------- combine conv partials -> interleaved output image ----------------
__global__ __launch_bounds__(256) void k_combine(const float* __restrict__ part, float* __restrict__ out) {
    int q = blockIdx.x * 256 + threadIdx.x;
    if (q >= 49152) return;
    int c = q >> 14;            // 0..2
    int r = q & 16383;
    int y = r >> 7, x = r & 127;
    float s = 0.f;
    #pragma unroll
    for (int uz = 0; uz < 16; ++uz) s += part[((uz * 3 + c) * 128 + y) * 128 + x];
    out[(y * 128 + x) * 3 + c] = s;
}

extern "C" void kernel_launch(void* const* d_in, const int* in_sizes, int n_in,
                              void* d_out, int out_size, void* d_ws, size_t ws_size,
                              hipStream_t stream) {
    const float* img = (const float*)d_in[0];    // (128,128,3) f32
    const float* depth = (const float*)d_in[1];  // (128,128) f32
    float* out = (float*)d_out;                  // 49152 (image) + 198147 (psf)

    char* ws = (char*)d_ws;
    double* zs = (double*)ws;                          // [0]=z1, [1..3]=psf sums
    float2* bufA = (float2*)(ws + 64);                 // 3*NN2 complex
    float2* bufB = bufA + 3 * NN2;                     // 3*NN2 complex
    float* raw = (float*)(bufB + 3 * NN2);             // 3*PCH floats (padded planar psf)
    float* part = (float*)(ws + 64);                   // aliases bufA/bufB (dead after pass 4)

    k_reduce_depth<<<1, 256, 0, stream>>>(depth, zs);
    k_dft<-1, 0><<<dim3(NN, 3), 256, 0, stream>>>(nullptr, bufA, zs, nullptr, nullptr);
    k_dft<-1, 1><<<dim3(NN, 3), 256, 0, stream>>>(bufA, bufB, zs, nullptr, nullptr);
    k_dft< 1, 2><<<dim3(NN, 3), 256, 0, stream>>>(bufB, bufA, zs, nullptr, nullptr);
    k_dft< 1, 3><<<dim3(NN, 3), 256, 0, stream>>>(bufA, nullptr, zs, raw, zs + 1);
    k_psf_norm<<<dim3(259, 3), 256, 0, stream>>>(raw, zs, out + 49152);
    k_conv<<<dim3(64, 3, 16), 64, 0, stream>>>(img, raw, part);
    k_combine<<<192, 256, 0, stream>>>(part, out);
}

// Round 3
// 174.086 us; speedup vs baseline: 1.4539x; 1.0645x over previous
//
#include <hip/hip_runtime.h>
#include <math.h>

#define NN 257
#define NN2 66049        // 257*257
#define PROW 260         // padded psf row stride (floats), 16B-aligned rows
#define PCH (PROW * NN)  // floats per psf channel

static const double D_PI = 3.14159265358979323846;

__device__ __forceinline__ double lam_of(int c) {
    return c == 0 ? 610e-9 : (c == 1 ? 530e-9 : 470e-9);
}

// ---------------- kernel 1: z1 = mean(depth) + zero sums (block 0); img -> planar (blocks 1..192) ----------------
__global__ __launch_bounds__(256) void k_prep(const float* __restrict__ depth, const float* __restrict__ img,
                                              double* zs, float* __restrict__ imgp) {
    if (blockIdx.x == 0) {
        __shared__ double s[256];
        double acc = 0.0;
        for (int i = threadIdx.x; i < 16384; i += 256) acc += (double)depth[i];
        s[threadIdx.x] = acc;
        __syncthreads();
        for (int o = 128; o > 0; o >>= 1) {
            if (threadIdx.x < o) s[threadIdx.x] += s[threadIdx.x + o];
            __syncthreads();
        }
        if (threadIdx.x == 0) {
            zs[0] = s[0] / 16384.0;
            zs[1] = 0.0; zs[2] = 0.0; zs[3] = 0.0;
        }
    } else {
        int idx = (blockIdx.x - 1) * 256 + threadIdx.x;  // < 49152
        int c = idx / 16384;
        int r = idx & 16383;
        imgp[c * 16384 + r] = img[r * 3 + c];
    }
}

// ---------------- fused DFT pass, split: blockIdx.x = output-half h, 2 threads per output (t parity) ----------------
// out[c][b][a] = sum_t colval(t) * exp(SIGN*2*pi*i*a*t/257)
// MODE 0: colval generated analytically (fftshift'd aperture field)
// MODE 1: colval = in[c][t][b]
// MODE 2: colval = in[c][t][b] * fftshift(H)(t,b)
// MODE 3: like 1, epilogue writes |.|^2/N^4 ifftshift'd to raw (padded planar) + channel sums
template <int SIGN, int MODE>
__global__ __launch_bounds__(256) void k_dft(const float2* __restrict__ in, float2* __restrict__ out,
                                             const double* __restrict__ zs, float* __restrict__ raw,
                                             double* __restrict__ sums) {
    __shared__ float2 col[NN];
    __shared__ float2 sacc[128];
    __shared__ float2 red[4];
    __shared__ double redd[4];
    const int h = blockIdx.x;   // 0/1: output half
    const int b = blockIdx.y;
    const int c = blockIdx.z;
    const int tid = threadIdx.x;

    // ---- stage column (fused generation / H-multiply) ----
    for (int t = tid; t < NN; t += 256) {
        float2 v;
        if (MODE == 0) {
            int js = t + 129; if (js >= NN) js -= NN;
            int is = b + 129; if (is >= NN) is -= NN;
            const double step = 0.01 / 256.0;
            double x = -0.005 + is * step;
            double y = -0.005 + js * step;
            double r2 = x * x + y * y;
            const double ap = 0.5 * (0.01 / 257.0) * 128.0 + 1e-7;
            v = make_float2(0.f, 0.f);
            if (sqrt(r2) <= ap) {
                double z1 = zs[0];
                double lam = lam_of(c);
                double th = fmod(2.0 * D_PI / lam * sqrt(r2 + z1 * z1), 2.0 * D_PI);
                double sv, cv; sincos(th, &sv, &cv);
                v = make_float2((float)cv, (float)sv);
            }
        } else {
            v = in[(c * NN + t) * NN + b];
            if (MODE == 2) {
                int ps = t + 129; if (ps >= NN) ps -= NN;
                int qs = b + 129; if (qs >= NN) qs -= NN;
                const double fstep = 25700.0 / 256.0;
                double fy = -12850.0 + ps * fstep;
                double fx = -12850.0 + qs * fstep;
                double lam = lam_of(c);
                double lfx = lam * fx, lfy = lam * fy;
                double a2 = 1.0 - lfx * lfx - lfy * lfy;
                float2 hh = make_float2(0.f, 0.f);
                if (fx * fx + fy * fy < 1.0 / (lam * lam)) {
                    double ph = fmod(2.0 * D_PI / lam * 0.05 * sqrt(a2 > 0.0 ? a2 : 0.0), 2.0 * D_PI);
                    double sv, cv; sincos(ph, &sv, &cv);
                    hh = make_float2((float)cv, (float)sv);
                }
                v = make_float2(v.x * hh.x - v.y * hh.y, v.x * hh.y + v.y * hh.x);
            }
        }
        col[t] = v;
    }
    __syncthreads();

    const float invn4 = (float)(1.0 / ((double)NN2 * (double)NN2));
    const int oa = h * 128 + (tid & 127);  // output index handled by this thread pair
    const int p = tid >> 7;                // t-parity

    double base = (double)SIGN * (2.0 * D_PI / 257.0) * (double)oa;
    double sb, cb; sincos(base, &sb, &cb);
    double s2, c2; sincos(2.0 * base, &s2, &c2);
    const float w2x = (float)c2, w2y = (float)s2;
    float cx, cy;
    if (p == 0) { cx = 1.f; cy = 0.f; } else { cx = (float)cb; cy = (float)sb; }
    float ax = 0.f, ay = 0.f;

    for (int k = 0; k < 128; ++k) {
        if ((k & 31) == 0 && k) {  // periodic refresh against f32 drift
            int t = p + 2 * k;
            int m = (oa * t) % 257;
            float g = (float)((double)SIGN * (2.0 * D_PI / 257.0) * (double)m);
            sincosf(g, &cy, &cx);
        }
        float2 v = col[p + 2 * k];
        ax = fmaf(v.x, cx, ax); ax = fmaf(-v.y, cy, ax);
        ay = fmaf(v.x, cy, ay); ay = fmaf(v.y, cx, ay);
        float nx = cx * w2x - cy * w2y;
        float ny = cx * w2y + cy * w2x;
        cx = nx; cy = ny;
    }
    if (p == 0) {  // extra term t=256: omega^{256a} = conj(omega^{a})
        float2 v = col[256];
        float ex = (float)cb, ey = (float)(-sb);
        ax = fmaf(v.x, ex, ax); ax = fmaf(-v.y, ey, ax);
        ay = fmaf(v.x, ey, ay); ay = fmaf(v.y, ex, ay);
    }

    // combine the two parity partials
    if (p == 1) sacc[tid & 127] = make_float2(ax, ay);
    __syncthreads();
    double sum_local = 0.0;
    if (p == 0) {
        float2 o2 = sacc[tid];
        float rx = ax + o2.x, ry = ay + o2.y;
        if (MODE < 3) {
            out[(c * NN + b) * NN + oa] = make_float2(rx, ry);
        } else {
            int jj = b + 129; if (jj >= NN) jj -= NN;
            int ii = oa + 129; if (ii >= NN) ii -= NN;
            float m = fmaf(rx, rx, ry * ry) * invn4;
            raw[c * PCH + jj * PROW + ii] = m;
            sum_local = (double)m;
        }
    }

    // ---- a = 256 output (h==1 blocks only): omega^{256 t} = omega^{-t}; block reduce ----
    if (h == 1) {
        float tx_, ty_;
        {
            int t = tid;
            float ang = (float)(-(double)SIGN * (2.0 * D_PI / 257.0) * (double)t);
            float s_, c_; sincosf(ang, &s_, &c_);
            float2 cv = col[t];
            tx_ = cv.x * c_ - cv.y * s_;
            ty_ = cv.x * s_ + cv.y * c_;
            if (tid == 0) {
                float ang2 = (float)(-(double)SIGN * (2.0 * D_PI / 257.0) * 256.0);
                sincosf(ang2, &s_, &c_);
                cv = col[256];
                tx_ += cv.x * c_ - cv.y * s_;
                ty_ += cv.x * s_ + cv.y * c_;
            }
        }
        for (int o = 32; o > 0; o >>= 1) {
            tx_ += __shfl_down(tx_, o);
            ty_ += __shfl_down(ty_, o);
        }
        int wid = tid >> 6;
        if ((tid & 63) == 0) red[wid] = make_float2(tx_, ty_);
        __syncthreads();
        if (tid == 0) {
            float Xx = red[0].x + red[1].x + red[2].x + red[3].x;
            float Xy = red[0].y + red[1].y + red[2].y + red[3].y;
            if (MODE < 3) {
                out[(c * NN + b) * NN + 256] = make_float2(Xx, Xy);
            } else {
                int jj = b + 129; if (jj >= NN) jj -= NN;
                float m = fmaf(Xx, Xx, Xy * Xy) * invn4;
                raw[c * PCH + jj * PROW + 128] = m;  // (256+129)%257 == 128
                sum_local += (double)m;
            }
        }
    }

    if (MODE == 3) {
        double s = sum_local;
        for (int o = 32; o > 0; o >>= 1) s += __shfl_down(s, o);
        int wid = tid >> 6;
        if ((tid & 63) == 0) redd[wid] = s;
        __syncthreads();
        if (tid == 0) atomicAdd(&sums[c], redd[0] + redd[1] + redd[2] + redd[3]);
    }
}

// ---------------- normalize psf -> interleaved output (raw left untouched) ----------------
__global__ __launch_bounds__(256) void k_psf_norm(const float* __restrict__ raw, const double* __restrict__ zs,
                                                  float* __restrict__ out_psf) {
    int c = blockIdx.y;
    int idx = blockIdx.x * 256 + threadIdx.x;
    if (idx >= NN2) return;
    int j = idx / NN, i = idx - j * NN;
    float inv = (float)(1.0 / (zs[1 + c] + 1e-7));
    out_psf[idx * 3 + c] = raw[c * PCH + j * PROW + i] * inv;
}

// ---------------- LDS-staged register-tiled SAME cross-correlation ----------------
// out[y][x] += sum img[u][v] * psf[u-y+128][v-x+128]  (on UNNORMALIZED raw psf)
// block: 128 thr; y-tile 8 (4 groups x 2y), x full 128 (4 per thread), u-chunk 8
__global__ __launch_bounds__(128) void k_conv(const float* __restrict__ imgp, const float* __restrict__ psf,
                                              float* __restrict__ part) {
    __shared__ float psft[15][264];  // rows kbase..kbase+14, +3 float shift for aligned windows
    __shared__ float simg[8][128];
    const int y0 = blockIdx.x * 8;
    const int c = blockIdx.y;
    const int uz = blockIdx.z;
    const int u0 = uz * 8;
    const int tid = threadIdx.x;
    const int tx = tid & 31, tyq = tid >> 5;  // tyq: 0..3 -> y pair
    const int x0 = 4 * tx;
    const int kbase = u0 - y0 + 121;

    // stage 15 psf rows (float4 global loads, scalar LDS stores at +3)
    for (int i = tid; i < 15 * 65; i += 128) {
        int r = i / 65, q = i - 65 * r;
        const float* src = psf + c * PCH + (kbase + r) * PROW;
        if (q < 64) {
            float4 A = *(const float4*)(src + 4 * q);
            psft[r][4 * q + 3] = A.x;
            psft[r][4 * q + 4] = A.y;
            psft[r][4 * q + 5] = A.z;
            psft[r][4 * q + 6] = A.w;
        } else {
            psft[r][259] = src[256];
        }
    }
    // stage 8 image rows
    for (int i = tid; i < 256; i += 128) {
        int uu = i >> 5, q = i & 31;
        *(float4*)&simg[uu][4 * q] = *(const float4*)(imgp + c * 16384 + (u0 + uu) * 128 + 4 * q);
    }
    __syncthreads();

    const int yyA = 2 * tyq;          // y = y0 + yyA, y0 + yyA + 1
    float4 accA = make_float4(0.f, 0.f, 0.f, 0.f);
    float4 accB = make_float4(0.f, 0.f, 0.f, 0.f);

    for (int uu = 0; uu < 8; ++uu) {
        const int rA = uu - yyA + 7;  // 1..14
        const float* rowA = &psft[rA][0];
        const float* rowB = &psft[rA - 1][0];
        const float* irow = &simg[uu][0];
        float4 PA = *(const float4*)(rowA + 128 - x0);
        float4 PB = *(const float4*)(rowB + 128 - x0);
        #pragma unroll 8
        for (int vb = 0; vb < 128; vb += 4) {
            float4 QA = *(const float4*)(rowA + vb - x0 + 132);
            float4 QB = *(const float4*)(rowB + vb - x0 + 132);
            float4 iv = *(const float4*)(irow + vb);
            accA.x = fmaf(iv.x, PA.w, accA.x); accA.x = fmaf(iv.y, QA.x, accA.x);
            accA.x = fmaf(iv.z, QA.y, accA.x); accA.x = fmaf(iv.w, QA.z, accA.x);
            accA.y = fmaf(iv.x, PA.z, accA.y); accA.y = fmaf(iv.y, PA.w, accA.y);
            accA.y = fmaf(iv.z, QA.x, accA.y); accA.y = fmaf(iv.w, QA.y, accA.y);
            accA.z = fmaf(iv.x, PA.y, accA.z); accA.z = fmaf(iv.y, PA.z, accA.z);
            accA.z = fmaf(iv.z, PA.w, accA.z); accA.z = fmaf(iv.w, QA.x, accA.z);
            accA.w = fmaf(iv.x, PA.x, accA.w); accA.w = fmaf(iv.y, PA.y, accA.w);
            accA.w = fmaf(iv.z, PA.z, accA.w); accA.w = fmaf(iv.w, PA.w, accA.w);
            accB.x = fmaf(iv.x, PB.w, accB.x); accB.x = fmaf(iv.y, QB.x, accB.x);
            accB.x = fmaf(iv.z, QB.y, accB.x); accB.x = fmaf(iv.w, QB.z, accB.x);
            accB.y = fmaf(iv.x, PB.z, accB.y); accB.y = fmaf(iv.y, PB.w, accB.y);
            accB.y = fmaf(iv.z, QB.x, accB.y); accB.y = fmaf(iv.w, QB.y, accB.y);
            accB.z = fmaf(iv.x, PB.y, accB.z); accB.z = fmaf(iv.y, PB.z, accB.z);
            accB.z = fmaf(iv.z, PB.w, accB.z); accB.z = fmaf(iv.w, QB.x, accB.z);
            accB.w = fmaf(iv.x, PB.x, accB.w); accB.w = fmaf(iv.y, PB.y, accB.w);
            accB.w = fmaf(iv.z, PB.z, accB.w); accB.w = fmaf(iv.w, PB.w, accB.w);
            PA = QA; PB = QB;
        }
    }
    // acc.x..w correspond to x = x0+0..3 but FMA mapping above is (dx0..dx3)->(x0+0..x0+3)
    const int yA = y0 + yyA;
    *(float4*)(part + ((uz * 3 + c) * 128 + yA) * 128 + x0) = accA;
    *(float4*)(part + ((uz * 3 + c) * 128 + yA + 1) * 128 + x0) = accB;
}

// ---------------- combine conv partials, apply 1/sum -> interleaved output image ----------------
__global__ __launch_bounds__(256) void k_combine(const float* __restrict__ part, const double* __restrict__ zs,
                                                 float* __restrict__ out) {
    int q = blockIdx.x * 256 + threadIdx.x;
    if (q >= 49152) return;
    int c = q >> 14;
    int r = q & 16383;
    float s = 0.f;
    #pragma unroll
    for (int uz = 0; uz < 16; ++uz) s += part[((uz * 3 + c) * 128 + (r >> 7)) * 128 + (r & 127)];
    float inv = (float)(1.0 / (zs[1 + c] + 1e-7));
    out[r * 3 + c] = s * inv;
}

extern "C" void kernel_launch(void* const* d_in, const int* in_sizes, int n_in,
                              void* d_out, int out_size, void* d_ws, size_t ws_size,
                              hipStream_t stream) {
    const float* img = (const float*)d_in[0];    // (128,128,3) f32
    const float* depth = (const float*)d_in[1];  // (128,128) f32
    float* out = (float*)d_out;                  // 49152 (image) + 198147 (psf)

    char* ws = (char*)d_ws;
    double* zs = (double*)ws;                          // [0]=z1, [1..3]=psf sums
    float2* bufA = (float2*)(ws + 64);                 // 3*NN2 complex
    float2* bufB = bufA + 3 * NN2;                     // 3*NN2 complex
    float* raw = (float*)(bufB + 3 * NN2);             // 3*PCH floats (padded planar |u|^2/N^4)
    float* imgp = raw + 3 * PCH;                       // 3*16384 planar image
    float* part = (float*)(ws + 64);                   // aliases bufA/bufB (dead after last dft)

    k_prep<<<193, 256, 0, stream>>>(depth, img, zs, imgp);
    k_dft<-1, 0><<<dim3(2, NN, 3), 256, 0, stream>>>(nullptr, bufA, zs, nullptr, nullptr);
    k_dft<-1, 1><<<dim3(2, NN, 3), 256, 0, stream>>>(bufA, bufB, zs, nullptr, nullptr);
    k_dft< 1, 2><<<dim3(2, NN, 3), 256, 0, stream>>>(bufB, bufA, zs, nullptr, nullptr);
    k_dft< 1, 3><<<dim3(2, NN, 3), 256, 0, stream>>>(bufA, nullptr, zs, raw, zs + 1);
    k_psf_norm<<<dim3(259, 3), 256, 0, stream>>>(raw, zs, out + 49152);
    k_conv<<<dim3(16, 3, 16), 128, 0, stream>>>(imgp, raw, part);
    k_combine<<<192, 256, 0, stream>>>(part, zs, out);
}

// Round 4
// 141.605 us; speedup vs baseline: 1.7873x; 1.2294x over previous
//
#include <hip/hip_runtime.h>
#include <math.h>

#define NN 257
#define NN2 66049        // 257*257
#define PROW 260         // padded psf row stride (floats), 16B-aligned rows
#define PCH (PROW * NN)  // floats per psf channel
#define NRZ 15           // psf-row chunks for conv (15 * 9 = 135 rows per y-tile)

static const double D_PI = 3.14159265358979323846;

__device__ __forceinline__ double lam_of(int c) {
    return c == 0 ? 610e-9 : (c == 1 ? 530e-9 : 470e-9);
}

// ---------------- kernel 1: depth mean (blk 0) + img transpose (blk 1..192) + twiddle table (blk 193) ----------------
__global__ __launch_bounds__(256) void k_prep(const float* __restrict__ depth, const float* __restrict__ img,
                                              double* zs, float* __restrict__ imgp, float2* __restrict__ twg) {
    if (blockIdx.x == 0) {
        __shared__ double s[256];
        double acc = 0.0;
        for (int i = threadIdx.x; i < 16384; i += 256) acc += (double)depth[i];
        s[threadIdx.x] = acc;
        __syncthreads();
        for (int o = 128; o > 0; o >>= 1) {
            if (threadIdx.x < o) s[threadIdx.x] += s[threadIdx.x + o];
            __syncthreads();
        }
        if (threadIdx.x == 0) {
            zs[0] = s[0] / 16384.0;
            zs[1] = 0.0; zs[2] = 0.0; zs[3] = 0.0;
        }
    } else if (blockIdx.x == 193) {
        int m = threadIdx.x;
        double th = 2.0 * D_PI * (double)m / 257.0;
        double sv, cv; sincos(th, &sv, &cv);
        twg[m] = make_float2((float)cv, (float)(-sv));   // exp(-2*pi*i*m/257)
        if (m == 0) {
            th = 2.0 * D_PI * 256.0 / 257.0;
            sincos(th, &sv, &cv);
            twg[256] = make_float2((float)cv, (float)(-sv));
        }
    } else {
        int idx = (blockIdx.x - 1) * 256 + threadIdx.x;  // < 49152
        int c = idx / 16384;
        int r = idx & 16383;
        imgp[c * 16384 + r] = img[r * 3 + c];
    }
}

// ---------------- kernel 2: fftshift'd aperture field -> w[c][t][b] ----------------
__global__ __launch_bounds__(256) void k_field(const double* __restrict__ zs, float2* __restrict__ w) {
    int idx = blockIdx.x * 256 + threadIdx.x;
    if (idx >= 3 * NN2) return;
    int c = idx / NN2;
    int r = idx - c * NN2;
    int t = r / NN, b = r - t * NN;
    int js = t + 129; if (js >= NN) js -= NN;
    int is = b + 129; if (is >= NN) is -= NN;
    const double step = 0.01 / 256.0;
    double x = -0.005 + is * step;
    double y = -0.005 + js * step;
    double r2 = x * x + y * y;
    const double ap = 0.5 * (0.01 / 257.0) * 128.0 + 1e-7;
    float2 o = make_float2(0.f, 0.f);
    if (sqrt(r2) <= ap) {
        double z1 = zs[0];
        double lam = lam_of(c);
        double th = fmod(2.0 * D_PI / lam * sqrt(r2 + z1 * z1), 2.0 * D_PI);
        double sv, cv; sincos(th, &sv, &cv);
        o = make_float2((float)cv, (float)sv);
    }
    w[idx] = o;
}

// ---------------- DFT pass: out[c][b][a] = sum_t colval(t) * exp(SIGN*2*pi*i*a*t/257) ----------------
// MODE 1: colval = in[c][t][b]
// MODE 2: colval = in[c][t][b] * fftshift(H)(t,b)
// MODE 3: epilogue writes |.|^2/N^4 ifftshift'd into raw (padded planar) + channel sums
template <int SIGN, int MODE>
__global__ __launch_bounds__(256) void k_dft(const float2* __restrict__ in, float2* __restrict__ out,
                                             const float2* __restrict__ twg, float* __restrict__ raw,
                                             double* __restrict__ sums) {
    __shared__ float2 col[NN];
    __shared__ float2 twL[NN];
    __shared__ float2 red[4];
    __shared__ double redd[4];
    const int h = blockIdx.x;   // output half
    const int b = blockIdx.y;
    const int c = blockIdx.z;
    const int tid = threadIdx.x;

    for (int t = tid; t < NN; t += 256) {
        twL[t] = twg[t];
        float2 v = in[(c * NN + t) * NN + b];
        if (MODE == 2) {
            int ps = t + 129; if (ps >= NN) ps -= NN;
            int qs = b + 129; if (qs >= NN) qs -= NN;
            const double fstep = 25700.0 / 256.0;
            double fy = -12850.0 + ps * fstep;
            double fx = -12850.0 + qs * fstep;
            double lam = lam_of(c);
            double lfx = lam * fx, lfy = lam * fy;
            double a2 = 1.0 - lfx * lfx - lfy * lfy;
            float2 hh = make_float2(0.f, 0.f);
            if (fx * fx + fy * fy < 1.0 / (lam * lam)) {
                double ph = fmod(2.0 * D_PI / lam * 0.05 * sqrt(a2 > 0.0 ? a2 : 0.0), 2.0 * D_PI);
                double sv, cv; sincos(ph, &sv, &cv);
                hh = make_float2((float)cv, (float)sv);
            }
            v = make_float2(v.x * hh.x - v.y * hh.y, v.x * hh.y + v.y * hh.x);
        }
        col[t] = v;
    }
    __syncthreads();

    const float invn4 = (float)(1.0 / ((double)NN2 * (double)NN2));
    const int oa = h * 128 + (tid & 127);
    const int p = tid >> 7;

    // twiddles from table: twL[m] = exp(-2*pi*i*m/257); omega^m = (twL.x, -SIGN*twL.y)
    float2 tb = twL[oa];
    const float cbx = tb.x, cby = -SIGN * tb.y;
    int m2 = 2 * oa; if (m2 >= 257) m2 -= 257;
    float2 t2 = twL[m2];
    const float w2x = t2.x, w2y = -SIGN * t2.y;
    float cx, cy;
    if (p == 0) { cx = 1.f; cy = 0.f; } else { cx = cbx; cy = cby; }
    float ax = 0.f, ay = 0.f;
    int mref = p ? oa : 0;
    const int d64 = (64 * oa) % 257;

    for (int k = 0; k < 128; ++k) {
        if ((k & 31) == 0 && k) {  // refresh from table (kills f32 drift)
            mref += d64; if (mref >= 257) mref -= 257;
            float2 tr = twL[mref];
            cx = tr.x; cy = -SIGN * tr.y;
        }
        float2 v = col[p + 2 * k];
        ax = fmaf(v.x, cx, ax); ax = fmaf(-v.y, cy, ax);
        ay = fmaf(v.x, cy, ay); ay = fmaf(v.y, cx, ay);
        float nx = cx * w2x - cy * w2y;
        float ny = fmaf(cx, w2y, cy * w2x);
        cx = nx; cy = ny;
    }
    if (p == 0) {  // t = 256: omega^{256*oa} = conj(omega^{oa})
        float2 v = col[256];
        float ex = cbx, ey = -cby;
        ax = fmaf(v.x, ex, ax); ax = fmaf(-v.y, ey, ax);
        ay = fmaf(v.x, ey, ay); ay = fmaf(v.y, ex, ay);
    }

    // combine parity partials via LDS (reuse twL space is unsafe; small array)
    __shared__ float2 sacc[128];
    if (p == 1) sacc[tid & 127] = make_float2(ax, ay);
    __syncthreads();
    double sum_local = 0.0;
    if (p == 0) {
        float2 o2 = sacc[tid];
        float rx = ax + o2.x, ry = ay + o2.y;
        if (MODE < 3) {
            out[(c * NN + b) * NN + oa] = make_float2(rx, ry);
        } else {
            int jj = b + 129; if (jj >= NN) jj -= NN;
            int ii = oa + 129; if (ii >= NN) ii -= NN;
            float m = fmaf(rx, rx, ry * ry) * invn4;
            raw[c * PCH + jj * PROW + ii] = m;
            sum_local = (double)m;
        }
    }

    // a = 256 output (h==1 blocks): coeff(t) = (twL[t].x, SIGN*twL[t].y)
    if (h == 1) {
        float c_ = twL[tid].x, s_ = SIGN * twL[tid].y;
        float2 cv = col[tid];
        float tx_ = cv.x * c_ - cv.y * s_;
        float ty_ = cv.x * s_ + cv.y * c_;
        if (tid == 0) {
            c_ = twL[256].x; s_ = SIGN * twL[256].y;
            cv = col[256];
            tx_ += cv.x * c_ - cv.y * s_;
            ty_ += cv.x * s_ + cv.y * c_;
        }
        for (int o = 32; o > 0; o >>= 1) {
            tx_ += __shfl_down(tx_, o);
            ty_ += __shfl_down(ty_, o);
        }
        int wid = tid >> 6;
        if ((tid & 63) == 0) red[wid] = make_float2(tx_, ty_);
        __syncthreads();
        if (tid == 0) {
            float Xx = red[0].x + red[1].x + red[2].x + red[3].x;
            float Xy = red[0].y + red[1].y + red[2].y + red[3].y;
            if (MODE < 3) {
                out[(c * NN + b) * NN + 256] = make_float2(Xx, Xy);
            } else {
                int jj = b + 129; if (jj >= NN) jj -= NN;
                float m = fmaf(Xx, Xx, Xy * Xy) * invn4;
                raw[c * PCH + jj * PROW + 128] = m;  // (256+129)%257 == 128
                sum_local += (double)m;
            }
        }
    }

    if (MODE == 3) {
        double s = sum_local;
        for (int o = 32; o > 0; o >>= 1) s += __shfl_down(s, o);
        int wid = tid >> 6;
        if ((tid & 63) == 0) redd[wid] = s;
        __syncthreads();
        if (tid == 0) atomicAdd(&sums[c], redd[0] + redd[1] + redd[2] + redd[3]);
    }
}

// ---------------- normalize psf -> interleaved output ----------------
__global__ __launch_bounds__(256) void k_psf_norm(const float* __restrict__ raw, const double* __restrict__ zs,
                                                  float* __restrict__ out_psf) {
    int c = blockIdx.y;
    int idx = blockIdx.x * 256 + threadIdx.x;
    if (idx >= NN2) return;
    int j = idx / NN, i = idx - j * NN;
    float inv = (float)(1.0 / (zs[1 + c] + 1e-7));
    out_psf[idx * 3 + c] = raw[c * PCH + j * PROW + i] * inv;
}

// ---------------- conv: flipped-psf LDS, lane-ascending windows, psf-row-chunk blocking ----------------
// out[y][x] = sum_r sum_v img[y+r-128][v] * psf[r][v-x+128];  F[rr][i] = psf[r0+rr][256-i]
// => psf[r][v-x+128] = F[rr][x-v+128]; thread: 1 y, 8 x, 4..5 r; all lanes share psf row (broadcast-dup)
__global__ __launch_bounds__(256) void k_conv(const float* __restrict__ imgp, const float* __restrict__ psf,
                                              float* __restrict__ part) {
    __shared__ float F[9][PROW];      // flipped psf rows r0..r0+8
    __shared__ float simg[16][128];   // img rows ulo..ulo+15 (zero outside [0,128))
    __shared__ float sacc[128][8];
    const int yt = blockIdx.x;   // 0..15 -> y-tile of 8
    const int rz = blockIdx.y;   // 0..14 -> 9 psf rows
    const int c = blockIdx.z;
    const int y0 = yt * 8;
    const int r0 = 121 - y0 + 9 * rz;   // r in [1, 255]
    const int tid = threadIdx.x;
    const int tx = tid & 15;
    const int tyq = (tid >> 4) & 7;
    const int rh = tid >> 7;
    const int x0 = 8 * tx;
    const int y = y0 + tyq;
    const int ulo = y0 + r0 - 128;

    // stage flipped psf rows: q<64: F[253-4q+s] = G[4q+3-s]; q==64: F[0] = G[256]
    for (int g = tid; g < 9 * 65; g += 256) {
        int rr = g / 65, q = g - 65 * rr;
        const float* G = psf + c * PCH + (r0 + rr) * PROW;
        float4 A = *(const float4*)(G + 4 * q);
        if (q < 64) {
            F[rr][256 - 4 * q] = A.x;
            F[rr][255 - 4 * q] = A.y;
            F[rr][254 - 4 * q] = A.z;
            F[rr][253 - 4 * q] = A.w;
        } else {
            F[rr][0] = A.x;
        }
    }
    // stage img rows (zero-padded outside)
    for (int g = tid; g < 512; g += 256) {
        int rrow = g >> 5, q = g & 31;
        int u = ulo + rrow;
        float4 v = make_float4(0.f, 0.f, 0.f, 0.f);
        if (u >= 0 && u < 128) v = *(const float4*)(imgp + c * 16384 + u * 128 + 4 * q);
        *(float4*)&simg[rrow][4 * q] = v;
    }
    __syncthreads();

    float4 aL = make_float4(0.f, 0.f, 0.f, 0.f);
    float4 aH = make_float4(0.f, 0.f, 0.f, 0.f);
    const int nrr = rh ? 4 : 5;
    const int rbase = rh ? 5 : 0;

    for (int rr4 = 0; rr4 < nrr; ++rr4) {
        const int rr = rbase + rr4;
        const int u = y + (r0 + rr) - 128;
        if (u < 0 || u > 127) continue;
        const float* Fr = &F[rr][0];
        const float* I = &simg[u - ulo][0];
        float4 W1 = *(const float4*)(Fr + x0 + 128);
        float4 W2 = *(const float4*)(Fr + x0 + 132);
        #pragma unroll 4
        for (int vb = 0; vb < 128; vb += 4) {
            float4 W0 = *(const float4*)(Fr + x0 + 124 - vb);
            float4 iv = *(const float4*)(I + vb);
            aL.x = fmaf(iv.x, W1.x, aL.x); aL.x = fmaf(iv.y, W0.w, aL.x); aL.x = fmaf(iv.z, W0.z, aL.x); aL.x = fmaf(iv.w, W0.y, aL.x);
            aL.y = fmaf(iv.x, W1.y, aL.y); aL.y = fmaf(iv.y, W1.x, aL.y); aL.y = fmaf(iv.z, W0.w, aL.y); aL.y = fmaf(iv.w, W0.z, aL.y);
            aL.z = fmaf(iv.x, W1.z, aL.z); aL.z = fmaf(iv.y, W1.y, aL.z); aL.z = fmaf(iv.z, W1.x, aL.z); aL.z = fmaf(iv.w, W0.w, aL.z);
            aL.w = fmaf(iv.x, W1.w, aL.w); aL.w = fmaf(iv.y, W1.z, aL.w); aL.w = fmaf(iv.z, W1.y, aL.w); aL.w = fmaf(iv.w, W1.x, aL.w);
            aH.x = fmaf(iv.x, W2.x, aH.x); aH.x = fmaf(iv.y, W1.w, aH.x); aH.x = fmaf(iv.z, W1.z, aH.x); aH.x = fmaf(iv.w, W1.y, aH.x);
            aH.y = fmaf(iv.x, W2.y, aH.y); aH.y = fmaf(iv.y, W2.x, aH.y); aH.y = fmaf(iv.z, W1.w, aH.y); aH.y = fmaf(iv.w, W1.z, aH.y);
            aH.z = fmaf(iv.x, W2.z, aH.z); aH.z = fmaf(iv.y, W2.y, aH.z); aH.z = fmaf(iv.z, W2.x, aH.z); aH.z = fmaf(iv.w, W1.w, aH.z);
            aH.w = fmaf(iv.x, W2.w, aH.w); aH.w = fmaf(iv.y, W2.z, aH.w); aH.w = fmaf(iv.z, W2.y, aH.w); aH.w = fmaf(iv.w, W2.x, aH.w);
            W2 = W1; W1 = W0;
        }
    }

    if (rh == 1) {
        int sl = tid & 127;
        *(float4*)&sacc[sl][0] = aL;
        *(float4*)&sacc[sl][4] = aH;
    }
    __syncthreads();
    if (rh == 0) {
        float4 bL = *(const float4*)&sacc[tid][0];
        float4 bH = *(const float4*)&sacc[tid][4];
        aL.x += bL.x; aL.y += bL.y; aL.z += bL.z; aL.w += bL.w;
        aH.x += bH.x; aH.y += bH.y; aH.z += bH.z; aH.w += bH.w;
        float* dst = part + ((rz * 3 + c) * 128 + y) * 128 + x0;
        *(float4*)dst = aL;
        *(float4*)(dst + 4) = aH;
    }
}

// ---------------- combine partials, apply 1/sum -> interleaved output image ----------------
__global__ __launch_bounds__(256) void k_combine(const float* __restrict__ part, const double* __restrict__ zs,
                                                 float* __restrict__ out) {
    int q = blockIdx.x * 256 + threadIdx.x;
    if (q >= 49152) return;
    int c = q >> 14;
    int r = q & 16383;
    float s = 0.f;
    #pragma unroll
    for (int rz = 0; rz < NRZ; ++rz) s += part[((rz * 3 + c) * 128 + (r >> 7)) * 128 + (r & 127)];
    float inv = (float)(1.0 / (zs[1 + c] + 1e-7));
    out[r * 3 + c] = s * inv;
}

extern "C" void kernel_launch(void* const* d_in, const int* in_sizes, int n_in,
                              void* d_out, int out_size, void* d_ws, size_t ws_size,
                              hipStream_t stream) {
    const float* img = (const float*)d_in[0];    // (128,128,3) f32
    const float* depth = (const float*)d_in[1];  // (128,128) f32
    float* out = (float*)d_out;                  // 49152 (image) + 198147 (psf)

    char* ws = (char*)d_ws;
    double* zs = (double*)ws;                          // [0]=z1, [1..3]=psf sums
    float2* bufA = (float2*)(ws + 64);                 // 3*NN2 complex
    float2* bufB = bufA + 3 * NN2;                     // 3*NN2 complex
    float* raw = (float*)(bufB + 3 * NN2);             // 3*PCH floats (padded planar |u|^2/N^4)
    float* imgp = raw + 3 * PCH;                       // 3*16384 planar image
    float2* twg = (float2*)(imgp + 3 * 16384);         // 257 twiddles
    float* part = (float*)(ws + 64);                   // aliases bufA+bufB (dead after last dft); NRZ*3*16384 floats

    k_prep<<<194, 256, 0, stream>>>(depth, img, zs, imgp, twg);
    k_field<<<(3 * NN2 + 255) / 256, 256, 0, stream>>>(zs, bufB);
    k_dft<-1, 1><<<dim3(2, NN, 3), 256, 0, stream>>>(bufB, bufA, twg, nullptr, nullptr);
    k_dft<-1, 1><<<dim3(2, NN, 3), 256, 0, stream>>>(bufA, bufB, twg, nullptr, nullptr);
    k_dft< 1, 2><<<dim3(2, NN, 3), 256, 0, stream>>>(bufB, bufA, twg, nullptr, nullptr);
    k_dft< 1, 3><<<dim3(2, NN, 3), 256, 0, stream>>>(bufA, nullptr, twg, raw, zs + 1);
    k_psf_norm<<<dim3(259, 3), 256, 0, stream>>>(raw, zs, out + 49152);
    k_conv<<<dim3(16, NRZ, 3), 256, 0, stream>>>(imgp, raw, part);
    k_combine<<<192, 256, 0, stream>>>(part, zs, out);
}

// Round 5
// 127.137 us; speedup vs baseline: 1.9907x; 1.1138x over previous
//
#include <hip/hip_runtime.h>
#include <math.h>

#define NN 257
#define NN2 66049        // 257*257
#define PROW 260         // padded psf row stride (floats), 16B-aligned rows
#define PCH (PROW * NN)  // floats per psf channel
#define NRZ 15           // psf-row chunks (15 * 9 = 135 rows per y-tile)
#define FSW 288          // swizzled flipped-psf row size

// granule swizzle: f multiple of 4 -> swizzled float offset (keeps 16B granules intact)
#define SWG(f) (((((f) >> 2) ^ (((f) >> 5) & 7)) << 2))
#define SW(f) (SWG(f) | ((f) & 3))

static const double D_PI = 3.14159265358979323846;

__device__ __forceinline__ double lam_of(int c) {
    return c == 0 ? 610e-9 : (c == 1 ? 530e-9 : 470e-9);
}

// fast accurate phase: exp(i*2*pi*rev), rev = dist/lam computed in f64, frac -> f32 hw sincos
__device__ __forceinline__ float2 phase_of(double rev) {
    rev -= floor(rev);
    float ang = (float)(2.0 * D_PI * rev);
    float sv, cv;
    __sincosf(ang, &sv, &cv);
    return make_float2(cv, sv);
}

// ---------------- kernel 1: depth mean (blk 0) + img transpose (blk 1..192) + twiddle table (blk 193) ----------------
__global__ __launch_bounds__(256) void k_prep(const float* __restrict__ depth, const float* __restrict__ img,
                                              double* zs, float* __restrict__ imgp, float2* __restrict__ twg) {
    if (blockIdx.x == 0) {
        __shared__ double s[256];
        double acc = 0.0;
        for (int i = threadIdx.x; i < 16384; i += 256) acc += (double)depth[i];
        s[threadIdx.x] = acc;
        __syncthreads();
        for (int o = 128; o > 0; o >>= 1) {
            if (threadIdx.x < o) s[threadIdx.x] += s[threadIdx.x + o];
            __syncthreads();
        }
        if (threadIdx.x == 0) {
            zs[0] = s[0] / 16384.0;
            zs[1] = 0.0; zs[2] = 0.0; zs[3] = 0.0;
        }
    } else if (blockIdx.x == 193) {
        int m = threadIdx.x;
        double th = 2.0 * D_PI * (double)m / 257.0;
        double sv, cv; sincos(th, &sv, &cv);
        twg[m] = make_float2((float)cv, (float)(-sv));   // exp(-2*pi*i*m/257)
        if (m == 0) {
            th = 2.0 * D_PI * 256.0 / 257.0;
            sincos(th, &sv, &cv);
            twg[256] = make_float2((float)cv, (float)(-sv));
        }
    } else {
        int idx = (blockIdx.x - 1) * 256 + threadIdx.x;  // < 49152
        int c = idx / 16384;
        int r = idx & 16383;
        imgp[c * 16384 + r] = img[r * 3 + c];
    }
}

// ---------------- kernel 2: fftshift'd aperture field -> w[c][t][b] ----------------
__global__ __launch_bounds__(256) void k_field(const double* __restrict__ zs, float2* __restrict__ w) {
    int idx = blockIdx.x * 256 + threadIdx.x;
    if (idx >= 3 * NN2) return;
    int c = idx / NN2;
    int r = idx - c * NN2;
    int t = r / NN, b = r - t * NN;
    int js = t + 129; if (js >= NN) js -= NN;
    int is = b + 129; if (is >= NN) is -= NN;
    const double step = 0.01 / 256.0;
    double x = -0.005 + is * step;
    double y = -0.005 + js * step;
    double r2 = x * x + y * y;
    const double ap = 0.5 * (0.01 / 257.0) * 128.0 + 1e-7;
    float2 o = make_float2(0.f, 0.f);
    if (sqrt(r2) <= ap) {
        double z1 = zs[0];
        o = phase_of(sqrt(r2 + z1 * z1) / lam_of(c));
    }
    w[idx] = o;
}

// ---------------- DFT pass: out[c][b][a] = sum_t colval(t) * exp(SIGN*2*pi*i*a*t/257) ----------------
// MODE 1: colval = in[c][t][b]
// MODE 2: colval = in[c][t][b] * fftshift(H)(t,b)
// MODE 3: epilogue writes |.|^2/N^4 ifftshift'd into raw (padded planar) + channel sums
template <int SIGN, int MODE>
__global__ __launch_bounds__(256) void k_dft(const float2* __restrict__ in, float2* __restrict__ out,
                                             const float2* __restrict__ twg, float* __restrict__ raw,
                                             double* __restrict__ sums) {
    __shared__ float2 col[NN];
    __shared__ float2 twL[NN];
    __shared__ float2 red[4];
    __shared__ double redd[4];
    const int h = blockIdx.x;   // output half
    const int b = blockIdx.y;
    const int c = blockIdx.z;
    const int tid = threadIdx.x;

    for (int t = tid; t < NN; t += 256) {
        twL[t] = twg[t];
        float2 v = in[(c * NN + t) * NN + b];
        if (MODE == 2) {
            int ps = t + 129; if (ps >= NN) ps -= NN;
            int qs = b + 129; if (qs >= NN) qs -= NN;
            const double fstep = 25700.0 / 256.0;
            double fy = -12850.0 + ps * fstep;
            double fx = -12850.0 + qs * fstep;
            double lam = lam_of(c);
            double lfx = lam * fx, lfy = lam * fy;
            double a2 = 1.0 - lfx * lfx - lfy * lfy;
            float2 hh = make_float2(0.f, 0.f);
            if (fx * fx + fy * fy < 1.0 / (lam * lam)) {
                hh = phase_of(0.05 / lam * sqrt(a2 > 0.0 ? a2 : 0.0));
            }
            v = make_float2(v.x * hh.x - v.y * hh.y, v.x * hh.y + v.y * hh.x);
        }
        col[t] = v;
    }
    __syncthreads();

    const float invn4 = (float)(1.0 / ((double)NN2 * (double)NN2));
    const int oa = h * 128 + (tid & 127);
    const int p = tid >> 7;

    // twiddles from table: twL[m] = exp(-2*pi*i*m/257); omega^m = (twL.x, -SIGN*twL.y)
    float2 tb = twL[oa];
    const float cbx = tb.x, cby = -SIGN * tb.y;
    int m2 = 2 * oa; if (m2 >= 257) m2 -= 257;
    float2 t2 = twL[m2];
    const float w2x = t2.x, w2y = -SIGN * t2.y;
    float cx, cy;
    if (p == 0) { cx = 1.f; cy = 0.f; } else { cx = cbx; cy = cby; }
    float ax = 0.f, ay = 0.f;
    int mref = p ? oa : 0;
    const int d64 = (64 * oa) % 257;

    for (int k = 0; k < 128; ++k) {
        if ((k & 31) == 0 && k) {  // refresh from table (kills f32 drift)
            mref += d64; if (mref >= 257) mref -= 257;
            float2 tr = twL[mref];
            cx = tr.x; cy = -SIGN * tr.y;
        }
        float2 v = col[p + 2 * k];
        ax = fmaf(v.x, cx, ax); ax = fmaf(-v.y, cy, ax);
        ay = fmaf(v.x, cy, ay); ay = fmaf(v.y, cx, ay);
        float nx = cx * w2x - cy * w2y;
        float ny = fmaf(cx, w2y, cy * w2x);
        cx = nx; cy = ny;
    }
    if (p == 0) {  // t = 256: omega^{256*oa} = conj(omega^{oa})
        float2 v = col[256];
        float ex = cbx, ey = -cby;
        ax = fmaf(v.x, ex, ax); ax = fmaf(-v.y, ey, ax);
        ay = fmaf(v.x, ey, ay); ay = fmaf(v.y, ex, ay);
    }

    __shared__ float2 sacc[128];
    if (p == 1) sacc[tid & 127] = make_float2(ax, ay);
    __syncthreads();
    double sum_local = 0.0;
    if (p == 0) {
        float2 o2 = sacc[tid];
        float rx = ax + o2.x, ry = ay + o2.y;
        if (MODE < 3) {
            out[(c * NN + b) * NN + oa] = make_float2(rx, ry);
        } else {
            int jj = b + 129; if (jj >= NN) jj -= NN;
            int ii = oa + 129; if (ii >= NN) ii -= NN;
            float m = fmaf(rx, rx, ry * ry) * invn4;
            raw[c * PCH + jj * PROW + ii] = m;
            sum_local = (double)m;
        }
    }

    // a = 256 output (h==1 blocks): coeff(t) = (twL[t].x, SIGN*twL[t].y)
    if (h == 1) {
        float c_ = twL[tid].x, s_ = SIGN * twL[tid].y;
        float2 cv = col[tid];
        float tx_ = cv.x * c_ - cv.y * s_;
        float ty_ = cv.x * s_ + cv.y * c_;
        if (tid == 0) {
            c_ = twL[256].x; s_ = SIGN * twL[256].y;
            cv = col[256];
            tx_ += cv.x * c_ - cv.y * s_;
            ty_ += cv.x * s_ + cv.y * c_;
        }
        for (int o = 32; o > 0; o >>= 1) {
            tx_ += __shfl_down(tx_, o);
            ty_ += __shfl_down(ty_, o);
        }
        int wid = tid >> 6;
        if ((tid & 63) == 0) red[wid] = make_float2(tx_, ty_);
        __syncthreads();
        if (tid == 0) {
            float Xx = red[0].x + red[1].x + red[2].x + red[3].x;
            float Xy = red[0].y + red[1].y + red[2].y + red[3].y;
            if (MODE < 3) {
                out[(c * NN + b) * NN + 256] = make_float2(Xx, Xy);
            } else {
                int jj = b + 129; if (jj >= NN) jj -= NN;
                float m = fmaf(Xx, Xx, Xy * Xy) * invn4;
                raw[c * PCH + jj * PROW + 128] = m;  // (256+129)%257 == 128
                sum_local += (double)m;
            }
        }
    }

    if (MODE == 3) {
        double s = sum_local;
        for (int o = 32; o > 0; o >>= 1) s += __shfl_down(s, o);
        int wid = tid >> 6;
        if ((tid & 63) == 0) redd[wid] = s;
        __syncthreads();
        if (tid == 0) atomicAdd(&sums[c], redd[0] + redd[1] + redd[2] + redd[3]);
    }
}

// ---------------- conv: swizzled flipped-psf LDS, padded img rows, 2y x 8x x (2-3)r per thread ----------------
// out[y][x] = sum_r sum_v img[y+r-128][v] * psf[r][v-x+128];  F[rr][sw(i)] = psf[r0+rr][256-i]
#define CMAP(aL, aH, iv)                                                                                              \
    aL.x = fmaf(iv.x, W1.x, aL.x); aL.x = fmaf(iv.y, W0.w, aL.x); aL.x = fmaf(iv.z, W0.z, aL.x); aL.x = fmaf(iv.w, W0.y, aL.x); \
    aL.y = fmaf(iv.x, W1.y, aL.y); aL.y = fmaf(iv.y, W1.x, aL.y); aL.y = fmaf(iv.z, W0.w, aL.y); aL.y = fmaf(iv.w, W0.z, aL.y); \
    aL.z = fmaf(iv.x, W1.z, aL.z); aL.z = fmaf(iv.y, W1.y, aL.z); aL.z = fmaf(iv.z, W1.x, aL.z); aL.z = fmaf(iv.w, W0.w, aL.z); \
    aL.w = fmaf(iv.x, W1.w, aL.w); aL.w = fmaf(iv.y, W1.z, aL.w); aL.w = fmaf(iv.z, W1.y, aL.w); aL.w = fmaf(iv.w, W1.x, aL.w); \
    aH.x = fmaf(iv.x, W2.x, aH.x); aH.x = fmaf(iv.y, W1.w, aH.x); aH.x = fmaf(iv.z, W1.z, aH.x); aH.x = fmaf(iv.w, W1.y, aH.x); \
    aH.y = fmaf(iv.x, W2.y, aH.y); aH.y = fmaf(iv.y, W2.x, aH.y); aH.y = fmaf(iv.z, W1.w, aH.y); aH.y = fmaf(iv.w, W1.z, aH.y); \
    aH.z = fmaf(iv.x, W2.z, aH.z); aH.z = fmaf(iv.y, W2.y, aH.z); aH.z = fmaf(iv.z, W2.x, aH.z); aH.z = fmaf(iv.w, W1.w, aH.z); \
    aH.w = fmaf(iv.x, W2.w, aH.w); aH.w = fmaf(iv.y, W2.z, aH.w); aH.w = fmaf(iv.z, W2.y, aH.w); aH.w = fmaf(iv.w, W2.x, aH.w);

__global__ __launch_bounds__(256) void k_conv(const float* __restrict__ imgp, const float* __restrict__ psf,
                                              float* __restrict__ part) {
    __shared__ float F[9][FSW];       // flipped+swizzled psf rows r0..r0+8
    __shared__ float simg[16][132];   // img rows ulo..ulo+15, padded stride (zero outside [0,128))
    __shared__ float sacc[3][4][260];
    const int yt = blockIdx.x;   // 0..15
    const int rz = blockIdx.y;   // 0..14
    const int c = blockIdx.z;
    const int y0 = yt * 8;
    const int r0 = 121 - y0 + 9 * rz;   // psf rows r0..r0+8, in [1,255]
    const int tid = threadIdx.x;
    const int tx = tid & 15;
    const int tyb = (tid >> 4) & 3;   // 2 y rows each
    const int rh = tid >> 6;          // rr split: {0,1,2},{3,4},{5,6},{7,8}
    const int x0 = 8 * tx;
    const int ulo = y0 + r0 - 128;

    for (int g = tid; g < 9 * 65; g += 256) {
        int rr = g / 65, q = g - 65 * rr;
        const float* G = psf + c * PCH + (r0 + rr) * PROW + 4 * q;
        float4 A = *(const float4*)G;
        if (q < 64) {
            F[rr][SW(256 - 4 * q)] = A.x;
            F[rr][SW(255 - 4 * q)] = A.y;
            F[rr][SW(254 - 4 * q)] = A.z;
            F[rr][SW(253 - 4 * q)] = A.w;
        } else {
            F[rr][SW(0)] = A.x;
        }
    }
    for (int g = tid; g < 512; g += 256) {
        int rw = g >> 5, q = g & 31;
        int u = ulo + rw;
        float4 v = make_float4(0.f, 0.f, 0.f, 0.f);
        if (u >= 0 && u < 128) v = *(const float4*)(imgp + c * 16384 + u * 128 + 4 * q);
        *(float4*)&simg[rw][4 * q] = v;
    }
    __syncthreads();

    float4 aL0 = make_float4(0.f, 0.f, 0.f, 0.f), aH0 = aL0, aL1 = aL0, aH1 = aL0;
    const int rrbeg = (rh == 0) ? 0 : 2 * rh + 1;
    const int rrend = (rh == 0) ? 3 : 2 * rh + 3;

    for (int rr = rrbeg; rr < rrend; ++rr) {
        const float* Fr = &F[rr][0];
        const int ur = 2 * tyb + rr;
        const float* I0 = &simg[ur][0];
        const float* I1 = &simg[ur + 1][0];
        float4 W1 = *(const float4*)(Fr + SWG(x0 + 128));
        float4 W2 = *(const float4*)(Fr + SWG(x0 + 132));
        #pragma unroll 2
        for (int vb = 0; vb < 128; vb += 4) {
            float4 W0 = *(const float4*)(Fr + SWG(x0 + 124 - vb));
            float4 i0 = *(const float4*)(I0 + vb);
            float4 i1 = *(const float4*)(I1 + vb);
            CMAP(aL0, aH0, i0)
            CMAP(aL1, aH1, i1)
            W2 = W1; W1 = W0;
        }
    }

    if (rh != 0) {
        int s = tid & 63;
        *(float4*)&sacc[rh - 1][0][4 * s] = aL0;
        *(float4*)&sacc[rh - 1][1][4 * s] = aH0;
        *(float4*)&sacc[rh - 1][2][4 * s] = aL1;
        *(float4*)&sacc[rh - 1][3][4 * s] = aH1;
    }
    __syncthreads();
    if (rh == 0) {
        int s = tid;  // 0..63
        #pragma unroll
        for (int r = 0; r < 3; ++r) {
            float4 b0 = *(const float4*)&sacc[r][0][4 * s];
            float4 b1 = *(const float4*)&sacc[r][1][4 * s];
            float4 b2 = *(const float4*)&sacc[r][2][4 * s];
            float4 b3 = *(const float4*)&sacc[r][3][4 * s];
            aL0.x += b0.x; aL0.y += b0.y; aL0.z += b0.z; aL0.w += b0.w;
            aH0.x += b1.x; aH0.y += b1.y; aH0.z += b1.z; aH0.w += b1.w;
            aL1.x += b2.x; aL1.y += b2.y; aL1.z += b2.z; aL1.w += b2.w;
            aH1.x += b3.x; aH1.y += b3.y; aH1.z += b3.z; aH1.w += b3.w;
        }
        const int y = y0 + 2 * tyb;
        float* dst = part + ((rz * 3 + c) * 128 + y) * 128 + x0;
        *(float4*)dst = aL0;
        *(float4*)(dst + 4) = aH0;
        *(float4*)(dst + 128) = aL1;
        *(float4*)(dst + 132) = aH1;
    }
}

// ---------------- final: combine conv partials (gid<49152) + psf normalize (rest) ----------------
__global__ __launch_bounds__(256) void k_final(const float* __restrict__ part, const float* __restrict__ raw,
                                               const double* __restrict__ zs, float* __restrict__ out) {
    int gid = blockIdx.x * 256 + threadIdx.x;
    if (gid < 49152) {
        int c = gid >> 14;
        int r = gid & 16383;
        float s = 0.f;
        #pragma unroll
        for (int rz = 0; rz < NRZ; ++rz) s += part[((rz * 3 + c) * 128 + (r >> 7)) * 128 + (r & 127)];
        float inv = (float)(1.0 / (zs[1 + c] + 1e-7));
        out[r * 3 + c] = s * inv;
    } else {
        int o = gid - 49152;
        if (o < 3 * NN2) {
            int idx = o / 3, c = o - 3 * idx;
            int j = idx / NN, i = idx - NN * j;
            float inv = (float)(1.0 / (zs[1 + c] + 1e-7));
            out[49152 + o] = raw[c * PCH + j * PROW + i] * inv;
        }
    }
}

extern "C" void kernel_launch(void* const* d_in, const int* in_sizes, int n_in,
                              void* d_out, int out_size, void* d_ws, size_t ws_size,
                              hipStream_t stream) {
    const float* img = (const float*)d_in[0];    // (128,128,3) f32
    const float* depth = (const float*)d_in[1];  // (128,128) f32
    float* out = (float*)d_out;                  // 49152 (image) + 198147 (psf)

    char* ws = (char*)d_ws;
    double* zs = (double*)ws;                          // [0]=z1, [1..3]=psf sums
    float2* bufA = (float2*)(ws + 64);                 // 3*NN2 complex
    float2* bufB = bufA + 3 * NN2;                     // 3*NN2 complex
    float* raw = (float*)(bufB + 3 * NN2);             // 3*PCH floats (padded planar |u|^2/N^4)
    float* imgp = raw + 3 * PCH;                       // 3*16384 planar image
    float2* twg = (float2*)(imgp + 3 * 16384);         // 257 twiddles
    float* part = (float*)(ws + 64);                   // aliases bufA+bufB (dead after last dft); NRZ*3*16384 floats

    k_prep<<<194, 256, 0, stream>>>(depth, img, zs, imgp, twg);
    k_field<<<(3 * NN2 + 255) / 256, 256, 0, stream>>>(zs, bufB);
    k_dft<-1, 1><<<dim3(2, NN, 3), 256, 0, stream>>>(bufB, bufA, twg, nullptr, nullptr);
    k_dft<-1, 1><<<dim3(2, NN, 3), 256, 0, stream>>>(bufA, bufB, twg, nullptr, nullptr);
    k_dft< 1, 2><<<dim3(2, NN, 3), 256, 0, stream>>>(bufB, bufA, twg, nullptr, nullptr);
    k_dft< 1, 3><<<dim3(2, NN, 3), 256, 0, stream>>>(bufA, nullptr, twg, raw, zs + 1);
    k_conv<<<dim3(16, NRZ, 3), 256, 0, stream>>>(imgp, raw, part);
    k_final<<<(49152 + 3 * NN2 + 255) / 256, 256, 0, stream>>>(part, raw, zs, out);
}

// Round 6
// 110.952 us; speedup vs baseline: 2.2811x; 1.1459x over previous
//
#include <hip/hip_runtime.h>
#include <math.h>

#define NN 257
#define NN2 66049        // 257*257
#define PROW 260         // padded psf row stride (floats), 16B-aligned rows
#define PCH (PROW * NN)  // floats per psf channel
#define NRZ 15           // psf-row chunks (15 * 9 = 135 rows per y-tile)
#define FSW 288          // swizzled flipped-psf row size

// granule swizzle: f multiple of 4 -> swizzled float offset (keeps 16B granules intact)
#define SWG(f) (((((f) >> 2) ^ (((f) >> 5) & 7)) << 2))
#define SW(f) (SWG(f) | ((f) & 3))

static const double D_PI = 3.14159265358979323846;

__device__ __forceinline__ double lam_of(int c) {
    return c == 0 ? 610e-9 : (c == 1 ? 530e-9 : 470e-9);
}

// fast accurate phase: exp(i*2*pi*rev), rev = dist/lam computed in f64, frac -> f32 hw sincos
__device__ __forceinline__ float2 phase_of(double rev) {
    rev -= floor(rev);
    float ang = (float)(2.0 * D_PI * rev);
    float sv, cv;
    __sincosf(ang, &sv, &cv);
    return make_float2(cv, sv);
}

// ---------------- kernel 1: depth mean (blk 0) + img transpose (blk 1..192) + twiddle table (blk 193) ----------------
__global__ __launch_bounds__(256) void k_prep(const float* __restrict__ depth, const float* __restrict__ img,
                                              double* zs, float* __restrict__ imgp, float2* __restrict__ twg) {
    if (blockIdx.x == 0) {
        __shared__ double s[256];
        double acc = 0.0;
        for (int i = threadIdx.x; i < 16384; i += 256) acc += (double)depth[i];
        s[threadIdx.x] = acc;
        __syncthreads();
        for (int o = 128; o > 0; o >>= 1) {
            if (threadIdx.x < o) s[threadIdx.x] += s[threadIdx.x + o];
            __syncthreads();
        }
        if (threadIdx.x == 0) {
            zs[0] = s[0] / 16384.0;
            zs[1] = 0.0; zs[2] = 0.0; zs[3] = 0.0;
        }
    } else if (blockIdx.x == 193) {
        int m = threadIdx.x;
        double th = 2.0 * D_PI * (double)m / 257.0;
        double sv, cv; sincos(th, &sv, &cv);
        twg[m] = make_float2((float)cv, (float)(-sv));   // exp(-2*pi*i*m/257)
        if (m == 0) {
            th = 2.0 * D_PI * 256.0 / 257.0;
            sincos(th, &sv, &cv);
            twg[256] = make_float2((float)cv, (float)(-sv));
        }
    } else {
        int idx = (blockIdx.x - 1) * 256 + threadIdx.x;  // < 49152
        int c = idx / 16384;
        int r = idx & 16383;
        imgp[c * 16384 + r] = img[r * 3 + c];
    }
}

// ---------------- DFT pass: out[c][b][a] = sum_t colval(t,b) * exp(SIGN*2*pi*i*a*t/257) ----------------
// Two b-columns per block (b0 = 2*by, b1 = b0+1; by==128 -> duplicate b=256, masked in sums).
// MODE 0: colval generated analytically (fftshift'd aperture field), no input read
// MODE 1: colval = in[c][t][b]
// MODE 2: colval = in[c][t][b] * fftshift(H)(t,b)
// MODE 3: like 1; epilogue writes |.|^2/N^4 ifftshift'd into raw (padded planar) + channel sums
template <int SIGN, int MODE>
__global__ __launch_bounds__(256) void k_dft(const float2* __restrict__ in, float2* __restrict__ out,
                                             const float2* __restrict__ twg, const double* __restrict__ zs,
                                             float* __restrict__ raw, double* __restrict__ sums) {
    __shared__ float4 col[NN];       // {re0, im0, re1, im1}
    __shared__ float2 twL[NN];
    __shared__ float4 sacc[128];
    __shared__ float4 red[4];
    __shared__ double redd[4];
    const int h = blockIdx.x;        // output half
    const int by = blockIdx.y;       // b-pair
    const int c = blockIdx.z;
    const int bc0 = 2 * by;
    const int bc1 = (bc0 < 256) ? bc0 + 1 : 256;
    const float dupf = (bc1 == bc0) ? 0.f : 1.f;
    const int tid = threadIdx.x;

    // ---- stage two columns (fused generation / H-multiply) ----
    for (int t = tid; t < NN; t += 256) {
        twL[t] = twg[t];
        float2 v0, v1;
        if (MODE == 0) {
            int js = t + 129; if (js >= NN) js -= NN;
            const double step = 0.01 / 256.0;
            double yy = -0.005 + js * step;
            double z1 = zs[0];
            double lam = lam_of(c);
            const double ap = 0.5 * (0.01 / 257.0) * 128.0 + 1e-7;
            {
                int is = bc0 + 129; if (is >= NN) is -= NN;
                double x = -0.005 + is * step;
                double r2 = x * x + yy * yy;
                v0 = make_float2(0.f, 0.f);
                if (sqrt(r2) <= ap) v0 = phase_of(sqrt(r2 + z1 * z1) / lam);
            }
            {
                int is = bc1 + 129; if (is >= NN) is -= NN;
                double x = -0.005 + is * step;
                double r2 = x * x + yy * yy;
                v1 = make_float2(0.f, 0.f);
                if (sqrt(r2) <= ap) v1 = phase_of(sqrt(r2 + z1 * z1) / lam);
            }
        } else {
            v0 = in[(c * NN + t) * NN + bc0];
            v1 = in[(c * NN + t) * NN + bc1];
            if (MODE == 2) {
                int ps = t + 129; if (ps >= NN) ps -= NN;
                const double fstep = 25700.0 / 256.0;
                double fy = -12850.0 + ps * fstep;
                double lam = lam_of(c);
                double ilam2 = 1.0 / (lam * lam);
                double kzr = 0.05 / lam;
                {
                    int qs = bc0 + 129; if (qs >= NN) qs -= NN;
                    double fx = -12850.0 + qs * fstep;
                    double lfx = lam * fx, lfy = lam * fy;
                    double a2 = 1.0 - lfx * lfx - lfy * lfy;
                    float2 hh = make_float2(0.f, 0.f);
                    if (fx * fx + fy * fy < ilam2) hh = phase_of(kzr * sqrt(a2 > 0.0 ? a2 : 0.0));
                    v0 = make_float2(v0.x * hh.x - v0.y * hh.y, v0.x * hh.y + v0.y * hh.x);
                }
                {
                    int qs = bc1 + 129; if (qs >= NN) qs -= NN;
                    double fx = -12850.0 + qs * fstep;
                    double lfx = lam * fx, lfy = lam * fy;
                    double a2 = 1.0 - lfx * lfx - lfy * lfy;
                    float2 hh = make_float2(0.f, 0.f);
                    if (fx * fx + fy * fy < ilam2) hh = phase_of(kzr * sqrt(a2 > 0.0 ? a2 : 0.0));
                    v1 = make_float2(v1.x * hh.x - v1.y * hh.y, v1.x * hh.y + v1.y * hh.x);
                }
            }
        }
        col[t] = make_float4(v0.x, v0.y, v1.x, v1.y);
    }
    __syncthreads();

    const float invn4 = (float)(1.0 / ((double)NN2 * (double)NN2));
    const int oa = h * 128 + (tid & 127);
    const int p = tid >> 7;

    // 4 twiddle chains: t = p + 2m + 8j, m=0..3, j=0..31; step multiplier omega^{8*oa}
    // table: twL[m] = exp(-2*pi*i*m/257); omega^m = (twL[m].x, -SIGN*twL[m].y)
    float cxm[4], cym[4];
    #pragma unroll
    for (int m = 0; m < 4; ++m) {
        int sm = (oa * (p + 2 * m)) % 257;
        float2 tt = twL[sm];
        cxm[m] = tt.x; cym[m] = -SIGN * tt.y;
    }
    {
        // chains are independent; accumulate chains {0,1}->acc*0, {2,3}->acc*1 for ILP
    }
    int d8 = (8 * oa) % 257;
    float2 w8t = twL[d8];
    const float w8x = w8t.x, w8y = -SIGN * w8t.y;

    float A0x = 0.f, A0y = 0.f, A1x = 0.f, A1y = 0.f;  // col bc0
    float B0x = 0.f, B0y = 0.f, B1x = 0.f, B1y = 0.f;  // col bc1

    for (int j = 0; j < 32; ++j) {
        const int tbase = p + 8 * j;
        #pragma unroll
        for (int m = 0; m < 4; ++m) {
            float4 v = col[tbase + 2 * m];
            float cx = cxm[m], cy = cym[m];
            if (m < 2) {
                A0x = fmaf(v.x, cx, A0x); A0x = fmaf(-v.y, cy, A0x);
                A0y = fmaf(v.x, cy, A0y); A0y = fmaf(v.y, cx, A0y);
                B0x = fmaf(v.z, cx, B0x); B0x = fmaf(-v.w, cy, B0x);
                B0y = fmaf(v.z, cy, B0y); B0y = fmaf(v.w, cx, B0y);
            } else {
                A1x = fmaf(v.x, cx, A1x); A1x = fmaf(-v.y, cy, A1x);
                A1y = fmaf(v.x, cy, A1y); A1y = fmaf(v.y, cx, A1y);
                B1x = fmaf(v.z, cx, B1x); B1x = fmaf(-v.w, cy, B1x);
                B1y = fmaf(v.z, cy, B1y); B1y = fmaf(v.w, cx, B1y);
            }
            float nx = fmaf(cx, w8x, -cy * w8y);
            float ny = fmaf(cx, w8y, cy * w8x);
            cxm[m] = nx; cym[m] = ny;
        }
    }
    float ax0 = A0x + A1x, ay0 = A0y + A1y;
    float ax1 = B0x + B1x, ay1 = B0y + B1y;

    if (p == 0) {  // t = 256 term: omega^{256*oa} = conj(omega^{oa})
        float4 v = col[256];
        float2 tb = twL[oa];
        float ex = tb.x, ey = SIGN * tb.y;
        ax0 = fmaf(v.x, ex, ax0); ax0 = fmaf(-v.y, ey, ax0);
        ay0 = fmaf(v.x, ey, ay0); ay0 = fmaf(v.y, ex, ay0);
        ax1 = fmaf(v.z, ex, ax1); ax1 = fmaf(-v.w, ey, ax1);
        ay1 = fmaf(v.z, ey, ay1); ay1 = fmaf(v.w, ex, ay1);
    }

    if (p == 1) sacc[tid & 127] = make_float4(ax0, ay0, ax1, ay1);
    __syncthreads();
    double sum_local = 0.0;
    if (p == 0) {
        float4 o2 = sacc[tid];
        float rx0 = ax0 + o2.x, ry0 = ay0 + o2.y;
        float rx1 = ax1 + o2.z, ry1 = ay1 + o2.w;
        if (MODE < 3) {
            out[(c * NN + bc0) * NN + oa] = make_float2(rx0, ry0);
            out[(c * NN + bc1) * NN + oa] = make_float2(rx1, ry1);
        } else {
            int jj0 = bc0 + 129; if (jj0 >= NN) jj0 -= NN;
            int jj1 = bc1 + 129; if (jj1 >= NN) jj1 -= NN;
            int ii = oa + 129; if (ii >= NN) ii -= NN;
            float m0 = fmaf(rx0, rx0, ry0 * ry0) * invn4;
            float m1 = fmaf(rx1, rx1, ry1 * ry1) * invn4;
            raw[c * PCH + jj0 * PROW + ii] = m0;
            raw[c * PCH + jj1 * PROW + ii] = m1;
            sum_local = (double)m0 + (double)(dupf * m1);
        }
    }

    // ---- a = 256 output (h==1 blocks): coeff(t) = conj(omega^t) = (twL[t].x, SIGN*twL[t].y) ----
    if (h == 1) {
        float c_ = twL[tid].x, s_ = SIGN * twL[tid].y;
        float4 cv = col[tid];
        float tx0 = cv.x * c_ - cv.y * s_;
        float ty0 = cv.x * s_ + cv.y * c_;
        float tx1 = cv.z * c_ - cv.w * s_;
        float ty1 = cv.z * s_ + cv.w * c_;
        if (tid == 0) {
            c_ = twL[256].x; s_ = SIGN * twL[256].y;
            cv = col[256];
            tx0 += cv.x * c_ - cv.y * s_;
            ty0 += cv.x * s_ + cv.y * c_;
            tx1 += cv.z * c_ - cv.w * s_;
            ty1 += cv.z * s_ + cv.w * c_;
        }
        for (int o = 32; o > 0; o >>= 1) {
            tx0 += __shfl_down(tx0, o);
            ty0 += __shfl_down(ty0, o);
            tx1 += __shfl_down(tx1, o);
            ty1 += __shfl_down(ty1, o);
        }
        int wid = tid >> 6;
        if ((tid & 63) == 0) red[wid] = make_float4(tx0, ty0, tx1, ty1);
        __syncthreads();
        if (tid == 0) {
            float Xx0 = red[0].x + red[1].x + red[2].x + red[3].x;
            float Xy0 = red[0].y + red[1].y + red[2].y + red[3].y;
            float Xx1 = red[0].z + red[1].z + red[2].z + red[3].z;
            float Xy1 = red[0].w + red[1].w + red[2].w + red[3].w;
            if (MODE < 3) {
                out[(c * NN + bc0) * NN + 256] = make_float2(Xx0, Xy0);
                out[(c * NN + bc1) * NN + 256] = make_float2(Xx1, Xy1);
            } else {
                int jj0 = bc0 + 129; if (jj0 >= NN) jj0 -= NN;
                int jj1 = bc1 + 129; if (jj1 >= NN) jj1 -= NN;
                float m0 = fmaf(Xx0, Xx0, Xy0 * Xy0) * invn4;
                float m1 = fmaf(Xx1, Xx1, Xy1 * Xy1) * invn4;
                raw[c * PCH + jj0 * PROW + 128] = m0;  // (256+129)%257 == 128
                raw[c * PCH + jj1 * PROW + 128] = m1;
                sum_local += (double)m0 + (double)(dupf * m1);
            }
        }
    }

    if (MODE == 3) {
        double s = sum_local;
        for (int o = 32; o > 0; o >>= 1) s += __shfl_down(s, o);
        int wid = tid >> 6;
        if ((tid & 63) == 0) redd[wid] = s;
        __syncthreads();
        if (tid == 0) atomicAdd(&sums[c], redd[0] + redd[1] + redd[2] + redd[3]);
    }
}

// ---------------- conv: swizzled flipped-psf LDS, padded img rows, 2y x 8x x (2-3)r per thread ----------------
// out[y][x] = sum_r sum_v img[y+r-128][v] * psf[r][v-x+128];  F[rr][sw(i)] = psf[r0+rr][256-i]
#define CMAP(aL, aH, iv)                                                                                              \
    aL.x = fmaf(iv.x, W1.x, aL.x); aL.x = fmaf(iv.y, W0.w, aL.x); aL.x = fmaf(iv.z, W0.z, aL.x); aL.x = fmaf(iv.w, W0.y, aL.x); \
    aL.y = fmaf(iv.x, W1.y, aL.y); aL.y = fmaf(iv.y, W1.x, aL.y); aL.y = fmaf(iv.z, W0.w, aL.y); aL.y = fmaf(iv.w, W0.z, aL.y); \
    aL.z = fmaf(iv.x, W1.z, aL.z); aL.z = fmaf(iv.y, W1.y, aL.z); aL.z = fmaf(iv.z, W1.x, aL.z); aL.z = fmaf(iv.w, W0.w, aL.z); \
    aL.w = fmaf(iv.x, W1.w, aL.w); aL.w = fmaf(iv.y, W1.z, aL.w); aL.w = fmaf(iv.z, W1.y, aL.w); aL.w = fmaf(iv.w, W1.x, aL.w); \
    aH.x = fmaf(iv.x, W2.x, aH.x); aH.x = fmaf(iv.y, W1.w, aH.x); aH.x = fmaf(iv.z, W1.z, aH.x); aH.x = fmaf(iv.w, W1.y, aH.x); \
    aH.y = fmaf(iv.x, W2.y, aH.y); aH.y = fmaf(iv.y, W2.x, aH.y); aH.y = fmaf(iv.z, W1.w, aH.y); aH.y = fmaf(iv.w, W1.z, aH.y); \
    aH.z = fmaf(iv.x, W2.z, aH.z); aH.z = fmaf(iv.y, W2.y, aH.z); aH.z = fmaf(iv.z, W2.x, aH.z); aH.z = fmaf(iv.w, W1.w, aH.z); \
    aH.w = fmaf(iv.x, W2.w, aH.w); aH.w = fmaf(iv.y, W2.z, aH.w); aH.w = fmaf(iv.z, W2.y, aH.w); aH.w = fmaf(iv.w, W2.x, aH.w);

__global__ __launch_bounds__(256) void k_conv(const float* __restrict__ imgp, const float* __restrict__ psf,
                                              float* __restrict__ part) {
    __shared__ float F[9][FSW];       // flipped+swizzled psf rows r0..r0+8
    __shared__ float simg[16][132];   // img rows ulo..ulo+15, padded stride (zero outside [0,128))
    __shared__ float sacc[3][4][260];
    const int yt = blockIdx.x;   // 0..15
    const int rz = blockIdx.y;   // 0..14
    const int c = blockIdx.z;
    const int y0 = yt * 8;
    const int r0 = 121 - y0 + 9 * rz;   // psf rows r0..r0+8, in [1,255]
    const int tid = threadIdx.x;
    const int tx = tid & 15;
    const int tyb = (tid >> 4) & 3;   // 2 y rows each
    const int rh = tid >> 6;          // rr split: {0,1,2},{3,4},{5,6},{7,8}
    const int x0 = 8 * tx;
    const int ulo = y0 + r0 - 128;

    for (int g = tid; g < 9 * 65; g += 256) {
        int rr = g / 65, q = g - 65 * rr;
        const float* G = psf + c * PCH + (r0 + rr) * PROW + 4 * q;
        float4 A = *(const float4*)G;
        if (q < 64) {
            F[rr][SW(256 - 4 * q)] = A.x;
            F[rr][SW(255 - 4 * q)] = A.y;
            F[rr][SW(254 - 4 * q)] = A.z;
            F[rr][SW(253 - 4 * q)] = A.w;
        } else {
            F[rr][SW(0)] = A.x;
        }
    }
    for (int g = tid; g < 512; g += 256) {
        int rw = g >> 5, q = g & 31;
        int u = ulo + rw;
        float4 v = make_float4(0.f, 0.f, 0.f, 0.f);
        if (u >= 0 && u < 128) v = *(const float4*)(imgp + c * 16384 + u * 128 + 4 * q);
        *(float4*)&simg[rw][4 * q] = v;
    }
    __syncthreads();

    float4 aL0 = make_float4(0.f, 0.f, 0.f, 0.f), aH0 = aL0, aL1 = aL0, aH1 = aL0;
    const int rrbeg = (rh == 0) ? 0 : 2 * rh + 1;
    const int rrend = (rh == 0) ? 3 : 2 * rh + 3;

    for (int rr = rrbeg; rr < rrend; ++rr) {
        const float* Fr = &F[rr][0];
        const int ur = 2 * tyb + rr;
        const float* I0 = &simg[ur][0];
        const float* I1 = &simg[ur + 1][0];
        float4 W1 = *(const float4*)(Fr + SWG(x0 + 128));
        float4 W2 = *(const float4*)(Fr + SWG(x0 + 132));
        #pragma unroll 2
        for (int vb = 0; vb < 128; vb += 4) {
            float4 W0 = *(const float4*)(Fr + SWG(x0 + 124 - vb));
            float4 i0 = *(const float4*)(I0 + vb);
            float4 i1 = *(const float4*)(I1 + vb);
            CMAP(aL0, aH0, i0)
            CMAP(aL1, aH1, i1)
            W2 = W1; W1 = W0;
        }
    }

    if (rh != 0) {
        int s = tid & 63;
        *(float4*)&sacc[rh - 1][0][4 * s] = aL0;
        *(float4*)&sacc[rh - 1][1][4 * s] = aH0;
        *(float4*)&sacc[rh - 1][2][4 * s] = aL1;
        *(float4*)&sacc[rh - 1][3][4 * s] = aH1;
    }
    __syncthreads();
    if (rh == 0) {
        int s = tid;  // 0..63
        #pragma unroll
        for (int r = 0; r < 3; ++r) {
            float4 b0 = *(const float4*)&sacc[r][0][4 * s];
            float4 b1 = *(const float4*)&sacc[r][1][4 * s];
            float4 b2 = *(const float4*)&sacc[r][2][4 * s];
            float4 b3 = *(const float4*)&sacc[r][3][4 * s];
            aL0.x += b0.x; aL0.y += b0.y; aL0.z += b0.z; aL0.w += b0.w;
            aH0.x += b1.x; aH0.y += b1.y; aH0.z += b1.z; aH0.w += b1.w;
            aL1.x += b2.x; aL1.y += b2.y; aL1.z += b2.z; aL1.w += b2.w;
            aH1.x += b3.x; aH1.y += b3.y; aH1.z += b3.z; aH1.w += b3.w;
        }
        const int y = y0 + 2 * tyb;
        float* dst = part + ((rz * 3 + c) * 128 + y) * 128 + x0;
        *(float4*)dst = aL0;
        *(float4*)(dst + 4) = aH0;
        *(float4*)(dst + 128) = aL1;
        *(float4*)(dst + 132) = aH1;
    }
}

// ---------------- final: combine conv partials (gid<49152) + psf normalize (rest) ----------------
__global__ __launch_bounds__(256) void k_final(const float* __restrict__ part, const float* __restrict__ raw,
                                               const double* __restrict__ zs, float* __restrict__ out) {
    int gid = blockIdx.x * 256 + threadIdx.x;
    if (gid < 49152) {
        int c = gid >> 14;
        int r = gid & 16383;
        float s = 0.f;
        #pragma unroll
        for (int rz = 0; rz < NRZ; ++rz) s += part[((rz * 3 + c) * 128 + (r >> 7)) * 128 + (r & 127)];
        float inv = (float)(1.0 / (zs[1 + c] + 1e-7));
        out[r * 3 + c] = s * inv;
    } else {
        int o = gid - 49152;
        if (o < 3 * NN2) {
            int idx = o / 3, c = o - 3 * idx;
            int j = idx / NN, i = idx - NN * j;
            float inv = (float)(1.0 / (zs[1 + c] + 1e-7));
            out[49152 + o] = raw[c * PCH + j * PROW + i] * inv;
        }
    }
}

extern "C" void kernel_launch(void* const* d_in, const int* in_sizes, int n_in,
                              void* d_out, int out_size, void* d_ws, size_t ws_size,
                              hipStream_t stream) {
    const float* img = (const float*)d_in[0];    // (128,128,3) f32
    const float* depth = (const float*)d_in[1];  // (128,128) f32
    float* out = (float*)d_out;                  // 49152 (image) + 198147 (psf)

    char* ws = (char*)d_ws;
    double* zs = (double*)ws;                          // [0]=z1, [1..3]=psf sums
    float2* bufA = (float2*)(ws + 64);                 // 3*NN2 complex
    float2* bufB = bufA + 3 * NN2;                     // 3*NN2 complex
    float* raw = (float*)(bufB + 3 * NN2);             // 3*PCH floats (padded planar |u|^2/N^4)
    float* imgp = raw + 3 * PCH;                       // 3*16384 planar image
    float2* twg = (float2*)(imgp + 3 * 16384);         // 257 twiddles
    float* part = (float*)(ws + 64);                   // aliases bufA+bufB (dead after last dft); NRZ*3*16384 floats

    k_prep<<<194, 256, 0, stream>>>(depth, img, zs, imgp, twg);
    k_dft<-1, 0><<<dim3(2, 129, 3), 256, 0, stream>>>(nullptr, bufA, twg, zs, nullptr, nullptr);
    k_dft<-1, 1><<<dim3(2, 129, 3), 256, 0, stream>>>(bufA, bufB, twg, zs, nullptr, nullptr);
    k_dft< 1, 2><<<dim3(2, 129, 3), 256, 0, stream>>>(bufB, bufA, twg, zs, nullptr, nullptr);
    k_dft< 1, 3><<<dim3(2, 129, 3), 256, 0, stream>>>(bufA, nullptr, twg, zs, raw, zs + 1);
    k_conv<<<dim3(16, NRZ, 3), 256, 0, stream>>>(imgp, raw, part);
    k_final<<<(49152 + 3 * NN2 + 255) / 256, 256, 0, stream>>>(part, raw, zs, out);
}